// Round 6
// baseline (3545.267 us; speedup 1.0000x reference)
//
#include <hip/hip_runtime.h>
#include <math.h>

typedef __bf16 v8bf __attribute__((ext_vector_type(8)));
typedef __bf16 v4bf __attribute__((ext_vector_type(4)));
typedef float  v16f __attribute__((ext_vector_type(16)));
typedef float  v4f  __attribute__((ext_vector_type(4)));

#define EPS_BN 1e-5f
#define Q_TOTAL 16384
#define N_MEM   262144
#define SLICES  64
#define SLICE_LEN (N_MEM / SLICES)   /* 4096 */
#define CHUNK   128
#define NCHUNKS (SLICE_LEN / CHUNK)  /* 32 */

// async global->LDS, 16B/lane. LDS dest is wave-uniform base + lane*16, so
// the bank swizzle must be folded into the GLOBAL source addresses.
__device__ __forceinline__ void gload_lds16(const void* g, void* l) {
    __builtin_amdgcn_global_load_lds(
        (const __attribute__((address_space(1))) void*)g,
        (__attribute__((address_space(3))) void*)l, 16, 0, 0);
}

// ---------------------------------------------------------------------------
// conv0: [256,1,64,64] -> [256,16,32,32], 3x3 s2 p1 + BN + ReLU
__global__ void conv0_kernel(const float* __restrict__ x,
                             const float* __restrict__ w, const float* __restrict__ bias,
                             const float* __restrict__ gamma, const float* __restrict__ beta,
                             const float* __restrict__ mean, const float* __restrict__ var,
                             float* __restrict__ out) {
    int idx = blockIdx.x * 256 + threadIdx.x;
    int xo = idx & 31, yo = (idx >> 5) & 31, c = (idx >> 10) & 15, b = idx >> 14;
    const float* xp = x + (size_t)b * 4096;
    const float* wc = w + c * 9;
    float acc = 0.f;
#pragma unroll
    for (int dy = 0; dy < 3; ++dy) {
        int iy = 2 * yo + dy - 1;
        if (iy < 0) continue;
#pragma unroll
        for (int dx = 0; dx < 3; ++dx) {
            int ix = 2 * xo + dx - 1;
            if (ix < 0) continue;
            acc += wc[dy * 3 + dx] * xp[iy * 64 + ix];
        }
    }
    acc += bias[c];
    float sc = gamma[c] * rsqrtf(var[c] + EPS_BN);
    float v  = (acc - mean[c]) * sc + beta[c];
    out[idx] = fmaxf(v, 0.f);
}

// ---------------------------------------------------------------------------
// conv1: [256,16,32,32] -> [256,32,16,16]. LDS-staged per (image, 8-ch group).
__global__ void conv1_kernel(const float* __restrict__ in,
                             const float* __restrict__ w, const float* __restrict__ bias,
                             const float* __restrict__ gamma, const float* __restrict__ beta,
                             const float* __restrict__ mean, const float* __restrict__ var,
                             float* __restrict__ out) {
    __shared__ float in_s[16384];
    __shared__ float w_s[1152];
    __shared__ float sc_s[8], sh_s[8];
    int b = blockIdx.x >> 2, cg = blockIdx.x & 3;
    int t = threadIdx.x;
    const float4* ip4 = (const float4*)(in + (size_t)b * 16384);
    float4* is4 = (float4*)in_s;
    for (int i = t; i < 4096; i += 256) is4[i] = ip4[i];
    for (int i = t; i < 1152; i += 256) w_s[i] = w[cg * 1152 + i];
    if (t < 8) {
        int c = cg * 8 + t;
        float sc = gamma[c] * rsqrtf(var[c] + EPS_BN);
        sc_s[t] = sc;
        sh_s[t] = (bias[c] - mean[c]) * sc + beta[c];
    }
    __syncthreads();
    int xo = t & 15, yo = t >> 4;
    float acc[8];
#pragma unroll
    for (int c = 0; c < 8; ++c) acc[c] = 0.f;
    int iy0 = 2 * yo - 1, ix0 = 2 * xo - 1;
    for (int ci = 0; ci < 16; ++ci) {
        const float* base = in_s + ci * 1024;
        float r[9];
#pragma unroll
        for (int dy = 0; dy < 3; ++dy) {
            int iy = iy0 + dy;
            int iyc = iy < 0 ? 0 : iy;
#pragma unroll
            for (int dx = 0; dx < 3; ++dx) {
                int ix = ix0 + dx;
                int ixc = ix < 0 ? 0 : ix;
                float v = base[iyc * 32 + ixc];
                r[dy * 3 + dx] = (iy >= 0 && ix >= 0) ? v : 0.f;
            }
        }
#pragma unroll
        for (int c = 0; c < 8; ++c) {
            const float* wp = w_s + (c * 16 + ci) * 9;
#pragma unroll
            for (int k = 0; k < 9; ++k) acc[c] = fmaf(wp[k], r[k], acc[c]);
        }
    }
#pragma unroll
    for (int c = 0; c < 8; ++c) {
        float v = fmaf(acc[c], sc_s[c], sh_s[c]);
        out[((size_t)(b * 32 + cg * 8 + c) * 16 + yo) * 16 + xo] = fmaxf(v, 0.f);
    }
}

// ---------------------------------------------------------------------------
// conv2: [256,32,16,16] -> [256,64,8,8]. LDS-staged per (image, 16-ch group).
__global__ void conv2_kernel(const float* __restrict__ in,
                             const float* __restrict__ w, const float* __restrict__ bias,
                             const float* __restrict__ gamma, const float* __restrict__ beta,
                             const float* __restrict__ mean, const float* __restrict__ var,
                             float* __restrict__ out) {
    __shared__ float in_s[8192];
    __shared__ float w_s[4608];
    __shared__ float sc_s[16], sh_s[16];
    int b = blockIdx.x >> 2, cg = blockIdx.x & 3;
    int t = threadIdx.x;
    const float4* ip4 = (const float4*)(in + (size_t)b * 8192);
    float4* is4 = (float4*)in_s;
    for (int i = t; i < 2048; i += 256) is4[i] = ip4[i];
    for (int i = t; i < 4608; i += 256) w_s[i] = w[cg * 4608 + i];
    if (t < 16) {
        int c = cg * 16 + t;
        float sc = gamma[c] * rsqrtf(var[c] + EPS_BN);
        sc_s[t] = sc;
        sh_s[t] = (bias[c] - mean[c]) * sc + beta[c];
    }
    __syncthreads();
    int xo = t & 7, yo = (t >> 3) & 7, cs = t >> 6;
    float acc[4];
#pragma unroll
    for (int l = 0; l < 4; ++l) acc[l] = 0.f;
    int iy0 = 2 * yo - 1, ix0 = 2 * xo - 1;
    for (int ci = 0; ci < 32; ++ci) {
        const float* base = in_s + ci * 256;
        float r[9];
#pragma unroll
        for (int dy = 0; dy < 3; ++dy) {
            int iy = iy0 + dy;
            int iyc = iy < 0 ? 0 : iy;
#pragma unroll
            for (int dx = 0; dx < 3; ++dx) {
                int ix = ix0 + dx;
                int ixc = ix < 0 ? 0 : ix;
                float v = base[iyc * 16 + ixc];
                r[dy * 3 + dx] = (iy >= 0 && ix >= 0) ? v : 0.f;
            }
        }
#pragma unroll
        for (int l = 0; l < 4; ++l) {
            const float* wp = w_s + ((cs * 4 + l) * 32 + ci) * 9;
#pragma unroll
            for (int k = 0; k < 9; ++k) acc[l] = fmaf(wp[k], r[k], acc[l]);
        }
    }
#pragma unroll
    for (int l = 0; l < 4; ++l) {
        int c = cg * 16 + cs * 4 + l;
        float v = fmaf(acc[l], sc_s[cs * 4 + l], sh_s[cs * 4 + l]);
        out[((size_t)(b * 64 + c) * 8 + yo) * 8 + xo] = fmaxf(v, 0.f);
    }
}

// ---------------------------------------------------------------------------
// qnorm: y2 [256,64,8,8] -> transpose -> L2 normalize -> bf16; qsq from the
// bf16-rounded values. Also initializes mind2 (+inf) for the dist kernel.
__global__ void qnorm_kernel(const float* __restrict__ y2,
                             __bf16* __restrict__ q, float* __restrict__ qsq,
                             unsigned int* __restrict__ mind2) {
    __shared__ float  L1s[4096];
    __shared__ __bf16 L2s[4096];
    int b = blockIdx.x, t = threadIdx.x;          // 64 threads
    mind2[b * 64 + t] = 0x7f800000u;              // +inf init
    const float* src = y2 + (size_t)b * 4096;
    for (int i = t; i < 4096; i += 64) L1s[i] = src[i];
    __syncthreads();
    int p = t;
    float ss = 0.f;
    for (int d = 0; d < 64; ++d) { float v = L1s[d * 64 + p]; ss += v * v; }
    float inv = 1.f / fmaxf(sqrtf(ss), 1e-12f);
    float q2 = 0.f;
    for (int d = 0; d < 64; ++d) {
        float v = L1s[d * 64 + p] * inv;
        __bf16 bv = (__bf16)v;
        L2s[p * 64 + d] = bv;
        float fb = (float)bv;
        q2 += fb * fb;
    }
    qsq[b * 64 + p] = q2;
    __syncthreads();
    for (int p2 = 0; p2 < 64; ++p2)
        q[((size_t)(b * 64 + p2)) * 64 + t] = L2s[p2 * 64 + t];
}

// ---------------------------------------------------------------------------
// mbnorm v2: 16 threads/row, float4 per thread, 4-step 16-lane reduction,
// vectorized 8B bf16 store. msq := 1 in dist (unit rows).
__global__ void mbnorm_kernel(const float* __restrict__ mb,
                              __bf16* __restrict__ mbbf) {
    int tid = blockIdx.x * 256 + threadIdx.x;
    int row = tid >> 4, sub = tid & 15;
    const float4 v = *(const float4*)(mb + (size_t)row * 64 + sub * 4);
    float ss = v.x * v.x + v.y * v.y + v.z * v.z + v.w * v.w;
#pragma unroll
    for (int o = 1; o < 16; o <<= 1) ss += __shfl_xor(ss, o, 64);
    float inv = 1.f / fmaxf(sqrtf(ss), 1e-12f);
    v4bf o;
    o[0] = (__bf16)(v.x * inv);
    o[1] = (__bf16)(v.y * inv);
    o[2] = (__bf16)(v.z * inv);
    o[3] = (__bf16)(v.w * inv);
    *(v4bf*)(mbbf + (size_t)row * 64 + sub * 4) = o;
}

// ---------------------------------------------------------------------------
// dist v15 (resubmit — R5 bench was an infra failure, kernel re-audited:
// bounds exact, layouts verified against v14's proven fragment maps).
// OPERAND SWAP. v14 pinned at MfmaUtil 79 = measured 333.6us vs the
// 264.9us 16x16-pipe floor; 4 blocks/CU is the register wall (R3 spill proof:
// live set ~112 with A=q,B=mem). Swap roles: A = memory rows (LDS), B = q
// (regs). A/B frags of 16x16x32 share the same lane map (row/col=lane&15,
// k-granule=lane>>4) so offk/swizzle are reused verbatim; the C map becomes
// col=q, ROW=m — the max-over-m folds IN-LANE right after each chain:
// persistent state collapses to tmax[4] (was tmax[4][4]), acc 4xv4f transient,
// Z v4f. Live set ~90 regs => __launch_bounds__(256,5) fits WITHOUT spill =>
// 5 blocks/CU (LDS 5x32KB = 160KB exact). At 25.6% MfmaUtil per resident
// block, 5 blocks saturates the pipe. Epilogue: combine kblk groups via
// shfl_xor(16|32), lanes 0-15 issue 4 atomics each.
// Kill-check (R3 signature): WRITE_SIZE ballooning => spill => revert.
__global__ __launch_bounds__(256, 5)
void dist_kernel(const __bf16* __restrict__ q, const float* __restrict__ qsq,
                 const __bf16* __restrict__ mb,
                 unsigned int* __restrict__ mind2) {
    __shared__ __align__(16) __bf16 Bs[2][CHUNK * 64];   // 2 x 16 KB
    const int t = threadIdx.x;
    const int wave = t >> 6, lane = t & 63;
    const int c16 = lane & 15;        // q-col within tile / m-row selector
    const int kblk = lane >> 4;       // 0..3: k-granule / C-row group
    const int qbase = blockIdx.x * 256 + wave * 64;
    const int slice = blockIdx.y;

    // B operand: q fragments, 4 q-tiles x 2 ksteps (32 VGPR, persistent).
    v8bf b[4][2];
#pragma unroll
    for (int qt = 0; qt < 4; ++qt)
#pragma unroll
        for (int ks = 0; ks < 2; ++ks)
            b[qt][ks] = *(const v8bf*)(q + (size_t)(qbase + qt * 16 + c16) * 64
                                         + ks * 32 + kblk * 8);

    // per-(lane, q-tile) running max over this lane's m-rows (kblk*4..+3)
    float tmax[4];
#pragma unroll
    for (int qt = 0; qt < 4; ++qt) tmax[qt] = -3.0e38f;

    v4f Z;                            // hoisted zero C-operand (4 regs)
#pragma unroll
    for (int r = 0; r < 4; ++r) Z[r] = 0.f;

    // staging: granule g=j*256+t -> row g>>3, slot (g&7)^(row&7); granule j
    // at LDS offset j*4096 (j*32 ≡ 0 mod 8 -> swizzle j-invariant).
    const int r0 = t >> 3, c0 = (t & 7) ^ (r0 & 7);
    const __bf16* gp = mb + (size_t)slice * SLICE_LEN * 64 + r0 * 64 + c0 * 8;
    const int wbase = wave * 1024;

    // prologue: chunk 0 -> buf 0 (4 granules of 4KB)
#pragma unroll
    for (int j = 0; j < 4; ++j) {
        gload_lds16(gp, (char*)Bs[0] + j * 4096 + wbase);
        gp += 2048;
    }

    // ds_read offsets: data k-granule κ = kblk + 4*ks at physical slot
    // κ ^ (row&7); row = c16 -> byte = c16*128 + ((κ ^ (lane&7))<<4).
    const int rowb = c16 * 128;
    int offk[2];
#pragma unroll
    for (int ks = 0; ks < 2; ++ks) offk[ks] = (((kblk + 4 * ks) ^ (lane & 7)) << 4);

#define MF16(A, B, C) __builtin_amdgcn_mfma_f32_16x16x32_bf16((A), (B), (C), 0, 0, 0)

    // one m-tile: 4 indep chains (one per q-tile) of length 2, then in-lane
    // fold of each chain's 4 m-rows into the running tmax.
    auto tilecomp = [&](v8bf a0, v8bf a1) {
        v4f c0 = MF16(a0, b[0][0], Z);
        v4f c1 = MF16(a0, b[1][0], Z);
        v4f c2 = MF16(a0, b[2][0], Z);
        v4f c3 = MF16(a0, b[3][0], Z);
        c0 = MF16(a1, b[0][1], c0);
        c1 = MF16(a1, b[1][1], c1);
        c2 = MF16(a1, b[2][1], c2);
        c3 = MF16(a1, b[3][1], c3);
        tmax[0] = fmaxf(tmax[0], fmaxf(fmaxf(c0[0], c0[1]), fmaxf(c0[2], c0[3])));
        tmax[1] = fmaxf(tmax[1], fmaxf(fmaxf(c1[0], c1[1]), fmaxf(c1[2], c1[3])));
        tmax[2] = fmaxf(tmax[2], fmaxf(fmaxf(c2[0], c2[1]), fmaxf(c2[2], c2[3])));
        tmax[3] = fmaxf(tmax[3], fmaxf(fmaxf(c3[0], c3[1]), fmaxf(c3[2], c3[3])));
    };

    auto step = [&](const char* bp, char* pdst, bool more) {
        __syncthreads();              // drains staging (vmcnt0) + sync
        if (more) {
#pragma unroll
            for (int j = 0; j < 4; ++j) {
                gload_lds16(gp, pdst + j * 4096 + wbase);
                gp += 2048;
            }
        }
        const char* tp = bp + rowb;
        // 8 m-tiles of 16 rows; rolling prefetch with named regs (no runtime
        // indexing -> stays in registers).
        v8bf aA0 = *(const v8bf*)(tp + offk[0]);
        v8bf aA1 = *(const v8bf*)(tp + offk[1]);
#pragma unroll
        for (int mt = 0; mt < 8; mt += 2) {
            v8bf aB0 = *(const v8bf*)(tp + (mt + 1) * 2048 + offk[0]);
            v8bf aB1 = *(const v8bf*)(tp + (mt + 1) * 2048 + offk[1]);
            tilecomp(aA0, aA1);
            if (mt + 2 < 8) {
                aA0 = *(const v8bf*)(tp + (mt + 2) * 2048 + offk[0]);
                aA1 = *(const v8bf*)(tp + (mt + 2) * 2048 + offk[1]);
            }
            tilecomp(aB0, aB1);
        }
    };

    for (int ch = 0; ch < NCHUNKS; ch += 2) {
        step((const char*)Bs[0], (char*)Bs[1], ch + 1 < NCHUNKS);
        step((const char*)Bs[1], (char*)Bs[0], ch + 2 < NCHUNKS);
    }
#undef MF16

    // combine the 4 kblk groups (disjoint m-row subsets) per q-col
#pragma unroll
    for (int qt = 0; qt < 4; ++qt) {
        float v = tmax[qt];
        v = fmaxf(v, __shfl_xor(v, 16, 64));
        v = fmaxf(v, __shfl_xor(v, 32, 64));
        tmax[qt] = v;
    }
    if (kblk == 0) {
#pragma unroll
        for (int qt = 0; qt < 4; ++qt) {
            int qi = qbase + qt * 16 + c16;
            // d^2 = qsq + |m|^2 - 2 dot, |m|^2 := 1 (unit rows)
            float dd = fmaxf(qsq[qi] + 1.0f - 2.0f * tmax[qt], 0.f);
            atomicMin(mind2 + qi, __float_as_uint(dd));
        }
    }
}

// finalize: out[b] = max_p sqrt(mind2[b*64+p])
__global__ void finalize_kernel(const unsigned int* __restrict__ mind2,
                                float* __restrict__ out) {
    int b = blockIdx.x, l = threadIdx.x;
    float v = __uint_as_float(mind2[b * 64 + l]);
    float d = sqrtf(fmaxf(v, 0.f));
#pragma unroll
    for (int o = 1; o < 64; o <<= 1) d = fmaxf(d, __shfl_xor(d, o, 64));
    if (l == 0) out[b] = d;
}

// ---------------------------------------------------------------------------
extern "C" void kernel_launch(void* const* d_in, const int* in_sizes, int n_in,
                              void* d_out, int out_size, void* d_ws, size_t ws_size,
                              hipStream_t stream) {
    (void)in_sizes; (void)n_in; (void)out_size; (void)ws_size;
    const float* x     = (const float*)d_in[0];
    const float* mbank = (const float*)d_in[1];
    const float* w0 = (const float*)d_in[2],  *b0 = (const float*)d_in[3];
    const float* g0 = (const float*)d_in[4],  *be0 = (const float*)d_in[5];
    const float* mn0 = (const float*)d_in[6], *vr0 = (const float*)d_in[7];
    const float* w1 = (const float*)d_in[8],  *b1 = (const float*)d_in[9];
    const float* g1 = (const float*)d_in[10], *be1 = (const float*)d_in[11];
    const float* mn1 = (const float*)d_in[12], *vr1 = (const float*)d_in[13];
    const float* w2 = (const float*)d_in[14], *b2 = (const float*)d_in[15];
    const float* g2 = (const float*)d_in[16], *be2 = (const float*)d_in[17];
    const float* mn2 = (const float*)d_in[18], *vr2 = (const float*)d_in[19];

    char* ws = (char*)d_ws;
    float*        y0    = (float*)(ws + 0);              // 16.78 MB
    float*        y1    = (float*)(ws + 16777216);       // 8.39 MB
    float*        y2    = (float*)(ws + 25165824);       // 4.19 MB
    __bf16*       qbf   = (__bf16*)(ws + 29360128);      // 2.10 MB
    float*        qsq   = (float*)(ws + 31457280);       // 64 KB
    __bf16*       mbbf  = (__bf16*)(ws + 31522816);      // 33.55 MB
    unsigned int* mind2 = (unsigned int*)(ws + 66125824);// 64 KB

    conv0_kernel<<<16384, 256, 0, stream>>>(x, w0, b0, g0, be0, mn0, vr0, y0);
    conv1_kernel<<<1024, 256, 0, stream>>>(y0, w1, b1, g1, be1, mn1, vr1, y1);
    conv2_kernel<<<1024, 256, 0, stream>>>(y1, w2, b2, g2, be2, mn2, vr2, y2);
    qnorm_kernel<<<256, 64, 0, stream>>>(y2, qbf, qsq, mind2);
    mbnorm_kernel<<<16384, 256, 0, stream>>>(mbank, mbbf);
    dist_kernel<<<dim3(64, SLICES), 256, 0, stream>>>(qbf, qsq, mbbf, mind2);
    finalize_kernel<<<256, 64, 0, stream>>>(mind2, (float*)d_out);
}

// Round 7
// 1929.149 us; speedup vs baseline: 1.8377x; 1.8377x over previous
//
#include <hip/hip_runtime.h>
#include <math.h>

typedef __bf16 v8bf __attribute__((ext_vector_type(8)));
typedef __bf16 v4bf __attribute__((ext_vector_type(4)));
typedef float  v16f __attribute__((ext_vector_type(16)));
typedef float  v4f  __attribute__((ext_vector_type(4)));

#define EPS_BN 1e-5f
#define Q_TOTAL 16384
#define N_MEM   262144
#define SLICES  64
#define SLICE_LEN (N_MEM / SLICES)   /* 4096 */
#define CHUNK   128
#define NCHUNKS (SLICE_LEN / CHUNK)  /* 32 */

// async global->LDS, 16B/lane. LDS dest is wave-uniform base + lane*16, so
// the bank swizzle must be folded into the GLOBAL source addresses.
__device__ __forceinline__ void gload_lds16(const void* g, void* l) {
    __builtin_amdgcn_global_load_lds(
        (const __attribute__((address_space(1))) void*)g,
        (__attribute__((address_space(3))) void*)l, 16, 0, 0);
}

// ---------------------------------------------------------------------------
// conv0: [256,1,64,64] -> [256,16,32,32], 3x3 s2 p1 + BN + ReLU
__global__ void conv0_kernel(const float* __restrict__ x,
                             const float* __restrict__ w, const float* __restrict__ bias,
                             const float* __restrict__ gamma, const float* __restrict__ beta,
                             const float* __restrict__ mean, const float* __restrict__ var,
                             float* __restrict__ out) {
    int idx = blockIdx.x * 256 + threadIdx.x;
    int xo = idx & 31, yo = (idx >> 5) & 31, c = (idx >> 10) & 15, b = idx >> 14;
    const float* xp = x + (size_t)b * 4096;
    const float* wc = w + c * 9;
    float acc = 0.f;
#pragma unroll
    for (int dy = 0; dy < 3; ++dy) {
        int iy = 2 * yo + dy - 1;
        if (iy < 0) continue;
#pragma unroll
        for (int dx = 0; dx < 3; ++dx) {
            int ix = 2 * xo + dx - 1;
            if (ix < 0) continue;
            acc += wc[dy * 3 + dx] * xp[iy * 64 + ix];
        }
    }
    acc += bias[c];
    float sc = gamma[c] * rsqrtf(var[c] + EPS_BN);
    float v  = (acc - mean[c]) * sc + beta[c];
    out[idx] = fmaxf(v, 0.f);
}

// ---------------------------------------------------------------------------
// conv1: [256,16,32,32] -> [256,32,16,16]. LDS-staged per (image, 8-ch group).
__global__ void conv1_kernel(const float* __restrict__ in,
                             const float* __restrict__ w, const float* __restrict__ bias,
                             const float* __restrict__ gamma, const float* __restrict__ beta,
                             const float* __restrict__ mean, const float* __restrict__ var,
                             float* __restrict__ out) {
    __shared__ float in_s[16384];
    __shared__ float w_s[1152];
    __shared__ float sc_s[8], sh_s[8];
    int b = blockIdx.x >> 2, cg = blockIdx.x & 3;
    int t = threadIdx.x;
    const float4* ip4 = (const float4*)(in + (size_t)b * 16384);
    float4* is4 = (float4*)in_s;
    for (int i = t; i < 4096; i += 256) is4[i] = ip4[i];
    for (int i = t; i < 1152; i += 256) w_s[i] = w[cg * 1152 + i];
    if (t < 8) {
        int c = cg * 8 + t;
        float sc = gamma[c] * rsqrtf(var[c] + EPS_BN);
        sc_s[t] = sc;
        sh_s[t] = (bias[c] - mean[c]) * sc + beta[c];
    }
    __syncthreads();
    int xo = t & 15, yo = t >> 4;
    float acc[8];
#pragma unroll
    for (int c = 0; c < 8; ++c) acc[c] = 0.f;
    int iy0 = 2 * yo - 1, ix0 = 2 * xo - 1;
    for (int ci = 0; ci < 16; ++ci) {
        const float* base = in_s + ci * 1024;
        float r[9];
#pragma unroll
        for (int dy = 0; dy < 3; ++dy) {
            int iy = iy0 + dy;
            int iyc = iy < 0 ? 0 : iy;
#pragma unroll
            for (int dx = 0; dx < 3; ++dx) {
                int ix = ix0 + dx;
                int ixc = ix < 0 ? 0 : ix;
                float v = base[iyc * 32 + ixc];
                r[dy * 3 + dx] = (iy >= 0 && ix >= 0) ? v : 0.f;
            }
        }
#pragma unroll
        for (int c = 0; c < 8; ++c) {
            const float* wp = w_s + (c * 16 + ci) * 9;
#pragma unroll
            for (int k = 0; k < 9; ++k) acc[c] = fmaf(wp[k], r[k], acc[c]);
        }
    }
#pragma unroll
    for (int c = 0; c < 8; ++c) {
        float v = fmaf(acc[c], sc_s[c], sh_s[c]);
        out[((size_t)(b * 32 + cg * 8 + c) * 16 + yo) * 16 + xo] = fmaxf(v, 0.f);
    }
}

// ---------------------------------------------------------------------------
// conv2: [256,32,16,16] -> [256,64,8,8]. LDS-staged per (image, 16-ch group).
__global__ void conv2_kernel(const float* __restrict__ in,
                             const float* __restrict__ w, const float* __restrict__ bias,
                             const float* __restrict__ gamma, const float* __restrict__ beta,
                             const float* __restrict__ mean, const float* __restrict__ var,
                             float* __restrict__ out) {
    __shared__ float in_s[8192];
    __shared__ float w_s[4608];
    __shared__ float sc_s[16], sh_s[16];
    int b = blockIdx.x >> 2, cg = blockIdx.x & 3;
    int t = threadIdx.x;
    const float4* ip4 = (const float4*)(in + (size_t)b * 8192);
    float4* is4 = (float4*)in_s;
    for (int i = t; i < 2048; i += 256) is4[i] = ip4[i];
    for (int i = t; i < 4608; i += 256) w_s[i] = w[cg * 4608 + i];
    if (t < 16) {
        int c = cg * 16 + t;
        float sc = gamma[c] * rsqrtf(var[c] + EPS_BN);
        sc_s[t] = sc;
        sh_s[t] = (bias[c] - mean[c]) * sc + beta[c];
    }
    __syncthreads();
    int xo = t & 7, yo = (t >> 3) & 7, cs = t >> 6;
    float acc[4];
#pragma unroll
    for (int l = 0; l < 4; ++l) acc[l] = 0.f;
    int iy0 = 2 * yo - 1, ix0 = 2 * xo - 1;
    for (int ci = 0; ci < 32; ++ci) {
        const float* base = in_s + ci * 256;
        float r[9];
#pragma unroll
        for (int dy = 0; dy < 3; ++dy) {
            int iy = iy0 + dy;
            int iyc = iy < 0 ? 0 : iy;
#pragma unroll
            for (int dx = 0; dx < 3; ++dx) {
                int ix = ix0 + dx;
                int ixc = ix < 0 ? 0 : ix;
                float v = base[iyc * 16 + ixc];
                r[dy * 3 + dx] = (iy >= 0 && ix >= 0) ? v : 0.f;
            }
        }
#pragma unroll
        for (int l = 0; l < 4; ++l) {
            const float* wp = w_s + ((cs * 4 + l) * 32 + ci) * 9;
#pragma unroll
            for (int k = 0; k < 9; ++k) acc[l] = fmaf(wp[k], r[k], acc[l]);
        }
    }
#pragma unroll
    for (int l = 0; l < 4; ++l) {
        int c = cg * 16 + cs * 4 + l;
        float v = fmaf(acc[l], sc_s[cs * 4 + l], sh_s[cs * 4 + l]);
        out[((size_t)(b * 64 + c) * 8 + yo) * 8 + xo] = fmaxf(v, 0.f);
    }
}

// ---------------------------------------------------------------------------
// qnorm: y2 [256,64,8,8] -> transpose -> L2 normalize -> bf16; qsq from the
// bf16-rounded values. Also initializes mind2 (+inf) for the dist kernel.
__global__ void qnorm_kernel(const float* __restrict__ y2,
                             __bf16* __restrict__ q, float* __restrict__ qsq,
                             unsigned int* __restrict__ mind2) {
    __shared__ float  L1s[4096];
    __shared__ __bf16 L2s[4096];
    int b = blockIdx.x, t = threadIdx.x;          // 64 threads
    mind2[b * 64 + t] = 0x7f800000u;              // +inf init
    const float* src = y2 + (size_t)b * 4096;
    for (int i = t; i < 4096; i += 64) L1s[i] = src[i];
    __syncthreads();
    int p = t;
    float ss = 0.f;
    for (int d = 0; d < 64; ++d) { float v = L1s[d * 64 + p]; ss += v * v; }
    float inv = 1.f / fmaxf(sqrtf(ss), 1e-12f);
    float q2 = 0.f;
    for (int d = 0; d < 64; ++d) {
        float v = L1s[d * 64 + p] * inv;
        __bf16 bv = (__bf16)v;
        L2s[p * 64 + d] = bv;
        float fb = (float)bv;
        q2 += fb * fb;
    }
    qsq[b * 64 + p] = q2;
    __syncthreads();
    for (int p2 = 0; p2 < 64; ++p2)
        q[((size_t)(b * 64 + p2)) * 64 + t] = L2s[p2 * 64 + t];
}

// ---------------------------------------------------------------------------
// mbnorm v2: 16 threads/row, float4 per thread, 4-step 16-lane reduction,
// vectorized 8B bf16 store. msq := 1 in dist (unit rows).
__global__ void mbnorm_kernel(const float* __restrict__ mb,
                              __bf16* __restrict__ mbbf) {
    int tid = blockIdx.x * 256 + threadIdx.x;
    int row = tid >> 4, sub = tid & 15;
    const float4 v = *(const float4*)(mb + (size_t)row * 64 + sub * 4);
    float ss = v.x * v.x + v.y * v.y + v.z * v.z + v.w * v.w;
#pragma unroll
    for (int o = 1; o < 16; o <<= 1) ss += __shfl_xor(ss, o, 64);
    float inv = 1.f / fmaxf(sqrtf(ss), 1e-12f);
    v4bf o;
    o[0] = (__bf16)(v.x * inv);
    o[1] = (__bf16)(v.y * inv);
    o[2] = (__bf16)(v.z * inv);
    o[3] = (__bf16)(v.w * inv);
    *(v4bf*)(mbbf + (size_t)row * 64 + sub * 4) = o;
}

// ---------------------------------------------------------------------------
// dist v16 = v15's operand-swap structure at __launch_bounds__(256,4).
// R6 proved the 102-reg budget (bound 5) is infeasible for ANY schedule the
// compiler emits here — transient pressure (overlapped tilecomp bodies:
// 2x{4 acc + 2 a-frags} + rolling prefetch) spills regardless of the smaller
// persistent set. Bound 4 (128 regs) is proven spill-free. Two outcomes:
//  - actual allocation <= 102 (persistent set IS 28 regs lighter than v14)
//    => HW grants 5 blocks/CU (LDS fits exactly) => MfmaUtil ~85-92, ~295us.
//  - allocation in (102,128] => 4 blocks/CU, v14-equivalent ~330us — a clean
//    79% plateau proof; future rounds then target the ~231us non-dist time.
// Kill-check: WRITE_SIZE must stay ~20MB (no scratch).
__global__ __launch_bounds__(256, 4)
void dist_kernel(const __bf16* __restrict__ q, const float* __restrict__ qsq,
                 const __bf16* __restrict__ mb,
                 unsigned int* __restrict__ mind2) {
    __shared__ __align__(16) __bf16 Bs[2][CHUNK * 64];   // 2 x 16 KB
    const int t = threadIdx.x;
    const int wave = t >> 6, lane = t & 63;
    const int c16 = lane & 15;        // q-col within tile / m-row selector
    const int kblk = lane >> 4;       // 0..3: k-granule / C-row group
    const int qbase = blockIdx.x * 256 + wave * 64;
    const int slice = blockIdx.y;

    // B operand: q fragments, 4 q-tiles x 2 ksteps (32 VGPR, persistent).
    v8bf b[4][2];
#pragma unroll
    for (int qt = 0; qt < 4; ++qt)
#pragma unroll
        for (int ks = 0; ks < 2; ++ks)
            b[qt][ks] = *(const v8bf*)(q + (size_t)(qbase + qt * 16 + c16) * 64
                                         + ks * 32 + kblk * 8);

    // per-(lane, q-tile) running max over this lane's m-rows (kblk*4..+3)
    float tmax[4];
#pragma unroll
    for (int qt = 0; qt < 4; ++qt) tmax[qt] = -3.0e38f;

    v4f Z;                            // hoisted zero C-operand (4 regs)
#pragma unroll
    for (int r = 0; r < 4; ++r) Z[r] = 0.f;

    // staging: granule g=j*256+t -> row g>>3, slot (g&7)^(row&7); granule j
    // at LDS offset j*4096 (j*32 ≡ 0 mod 8 -> swizzle j-invariant).
    const int r0 = t >> 3, c0 = (t & 7) ^ (r0 & 7);
    const __bf16* gp = mb + (size_t)slice * SLICE_LEN * 64 + r0 * 64 + c0 * 8;
    const int wbase = wave * 1024;

    // prologue: chunk 0 -> buf 0 (4 granules of 4KB)
#pragma unroll
    for (int j = 0; j < 4; ++j) {
        gload_lds16(gp, (char*)Bs[0] + j * 4096 + wbase);
        gp += 2048;
    }

    // ds_read offsets: data k-granule κ = kblk + 4*ks at physical slot
    // κ ^ (row&7); row = c16 -> byte = c16*128 + ((κ ^ (lane&7))<<4).
    const int rowb = c16 * 128;
    int offk[2];
#pragma unroll
    for (int ks = 0; ks < 2; ++ks) offk[ks] = (((kblk + 4 * ks) ^ (lane & 7)) << 4);

#define MF16(A, B, C) __builtin_amdgcn_mfma_f32_16x16x32_bf16((A), (B), (C), 0, 0, 0)

    // one m-tile: 4 indep chains (one per q-tile) of length 2, then in-lane
    // fold of each chain's 4 m-rows into the running tmax.
    auto tilecomp = [&](v8bf a0, v8bf a1) {
        v4f c0 = MF16(a0, b[0][0], Z);
        v4f c1 = MF16(a0, b[1][0], Z);
        v4f c2 = MF16(a0, b[2][0], Z);
        v4f c3 = MF16(a0, b[3][0], Z);
        c0 = MF16(a1, b[0][1], c0);
        c1 = MF16(a1, b[1][1], c1);
        c2 = MF16(a1, b[2][1], c2);
        c3 = MF16(a1, b[3][1], c3);
        tmax[0] = fmaxf(tmax[0], fmaxf(fmaxf(c0[0], c0[1]), fmaxf(c0[2], c0[3])));
        tmax[1] = fmaxf(tmax[1], fmaxf(fmaxf(c1[0], c1[1]), fmaxf(c1[2], c1[3])));
        tmax[2] = fmaxf(tmax[2], fmaxf(fmaxf(c2[0], c2[1]), fmaxf(c2[2], c2[3])));
        tmax[3] = fmaxf(tmax[3], fmaxf(fmaxf(c3[0], c3[1]), fmaxf(c3[2], c3[3])));
    };

    auto step = [&](const char* bp, char* pdst, bool more) {
        __syncthreads();              // drains staging (vmcnt0) + sync
        if (more) {
#pragma unroll
            for (int j = 0; j < 4; ++j) {
                gload_lds16(gp, pdst + j * 4096 + wbase);
                gp += 2048;
            }
        }
        const char* tp = bp + rowb;
        // 8 m-tiles of 16 rows; rolling prefetch with named regs (no runtime
        // indexing -> stays in registers).
        v8bf aA0 = *(const v8bf*)(tp + offk[0]);
        v8bf aA1 = *(const v8bf*)(tp + offk[1]);
#pragma unroll
        for (int mt = 0; mt < 8; mt += 2) {
            v8bf aB0 = *(const v8bf*)(tp + (mt + 1) * 2048 + offk[0]);
            v8bf aB1 = *(const v8bf*)(tp + (mt + 1) * 2048 + offk[1]);
            tilecomp(aA0, aA1);
            if (mt + 2 < 8) {
                aA0 = *(const v8bf*)(tp + (mt + 2) * 2048 + offk[0]);
                aA1 = *(const v8bf*)(tp + (mt + 2) * 2048 + offk[1]);
            }
            tilecomp(aB0, aB1);
        }
    };

    for (int ch = 0; ch < NCHUNKS; ch += 2) {
        step((const char*)Bs[0], (char*)Bs[1], ch + 1 < NCHUNKS);
        step((const char*)Bs[1], (char*)Bs[0], ch + 2 < NCHUNKS);
    }
#undef MF16

    // combine the 4 kblk groups (disjoint m-row subsets) per q-col
#pragma unroll
    for (int qt = 0; qt < 4; ++qt) {
        float v = tmax[qt];
        v = fmaxf(v, __shfl_xor(v, 16, 64));
        v = fmaxf(v, __shfl_xor(v, 32, 64));
        tmax[qt] = v;
    }
    if (kblk == 0) {
#pragma unroll
        for (int qt = 0; qt < 4; ++qt) {
            int qi = qbase + qt * 16 + c16;
            // d^2 = qsq + |m|^2 - 2 dot, |m|^2 := 1 (unit rows)
            float dd = fmaxf(qsq[qi] + 1.0f - 2.0f * tmax[qt], 0.f);
            atomicMin(mind2 + qi, __float_as_uint(dd));
        }
    }
}

// finalize: out[b] = max_p sqrt(mind2[b*64+p])
__global__ void finalize_kernel(const unsigned int* __restrict__ mind2,
                                float* __restrict__ out) {
    int b = blockIdx.x, l = threadIdx.x;
    float v = __uint_as_float(mind2[b * 64 + l]);
    float d = sqrtf(fmaxf(v, 0.f));
#pragma unroll
    for (int o = 1; o < 64; o <<= 1) d = fmaxf(d, __shfl_xor(d, o, 64));
    if (l == 0) out[b] = d;
}

// ---------------------------------------------------------------------------
extern "C" void kernel_launch(void* const* d_in, const int* in_sizes, int n_in,
                              void* d_out, int out_size, void* d_ws, size_t ws_size,
                              hipStream_t stream) {
    (void)in_sizes; (void)n_in; (void)out_size; (void)ws_size;
    const float* x     = (const float*)d_in[0];
    const float* mbank = (const float*)d_in[1];
    const float* w0 = (const float*)d_in[2],  *b0 = (const float*)d_in[3];
    const float* g0 = (const float*)d_in[4],  *be0 = (const float*)d_in[5];
    const float* mn0 = (const float*)d_in[6], *vr0 = (const float*)d_in[7];
    const float* w1 = (const float*)d_in[8],  *b1 = (const float*)d_in[9];
    const float* g1 = (const float*)d_in[10], *be1 = (const float*)d_in[11];
    const float* mn1 = (const float*)d_in[12], *vr1 = (const float*)d_in[13];
    const float* w2 = (const float*)d_in[14], *b2 = (const float*)d_in[15];
    const float* g2 = (const float*)d_in[16], *be2 = (const float*)d_in[17];
    const float* mn2 = (const float*)d_in[18], *vr2 = (const float*)d_in[19];

    char* ws = (char*)d_ws;
    float*        y0    = (float*)(ws + 0);              // 16.78 MB
    float*        y1    = (float*)(ws + 16777216);       // 8.39 MB
    float*        y2    = (float*)(ws + 25165824);       // 4.19 MB
    __bf16*       qbf   = (__bf16*)(ws + 29360128);      // 2.10 MB
    float*        qsq   = (float*)(ws + 31457280);       // 64 KB
    __bf16*       mbbf  = (__bf16*)(ws + 31522816);      // 33.55 MB
    unsigned int* mind2 = (unsigned int*)(ws + 66125824);// 64 KB

    conv0_kernel<<<16384, 256, 0, stream>>>(x, w0, b0, g0, be0, mn0, vr0, y0);
    conv1_kernel<<<1024, 256, 0, stream>>>(y0, w1, b1, g1, be1, mn1, vr1, y1);
    conv2_kernel<<<1024, 256, 0, stream>>>(y1, w2, b2, g2, be2, mn2, vr2, y2);
    qnorm_kernel<<<256, 64, 0, stream>>>(y2, qbf, qsq, mind2);
    mbnorm_kernel<<<16384, 256, 0, stream>>>(mbank, mbbf);
    dist_kernel<<<dim3(64, SLICES), 256, 0, stream>>>(qbf, qsq, mbbf, mind2);
    finalize_kernel<<<256, 64, 0, stream>>>(mind2, (float*)d_out);
}

// Round 8
// 616.126 us; speedup vs baseline: 5.7541x; 3.1311x over previous
//
#include <hip/hip_runtime.h>
#include <math.h>

typedef __bf16 v8bf __attribute__((ext_vector_type(8)));
typedef __bf16 v4bf __attribute__((ext_vector_type(4)));
typedef float  v16f __attribute__((ext_vector_type(16)));
typedef float  v4f  __attribute__((ext_vector_type(4)));

#define EPS_BN 1e-5f
#define Q_TOTAL 16384
#define N_MEM   262144
#define SLICES  64
#define SLICE_LEN (N_MEM / SLICES)   /* 4096 */
#define CHUNK   128
#define NCHUNKS (SLICE_LEN / CHUNK)  /* 32 */

// async global->LDS, 16B/lane. LDS dest is wave-uniform base + lane*16, so
// the bank swizzle must be folded into the GLOBAL source addresses.
__device__ __forceinline__ void gload_lds16(const void* g, void* l) {
    __builtin_amdgcn_global_load_lds(
        (const __attribute__((address_space(1))) void*)g,
        (__attribute__((address_space(3))) void*)l, 16, 0, 0);
}

// ---------------------------------------------------------------------------
// conv0: [256,1,64,64] -> [256,16,32,32], 3x3 s2 p1 + BN + ReLU
__global__ void conv0_kernel(const float* __restrict__ x,
                             const float* __restrict__ w, const float* __restrict__ bias,
                             const float* __restrict__ gamma, const float* __restrict__ beta,
                             const float* __restrict__ mean, const float* __restrict__ var,
                             float* __restrict__ out) {
    int idx = blockIdx.x * 256 + threadIdx.x;
    int xo = idx & 31, yo = (idx >> 5) & 31, c = (idx >> 10) & 15, b = idx >> 14;
    const float* xp = x + (size_t)b * 4096;
    const float* wc = w + c * 9;
    float acc = 0.f;
#pragma unroll
    for (int dy = 0; dy < 3; ++dy) {
        int iy = 2 * yo + dy - 1;
        if (iy < 0) continue;
#pragma unroll
        for (int dx = 0; dx < 3; ++dx) {
            int ix = 2 * xo + dx - 1;
            if (ix < 0) continue;
            acc += wc[dy * 3 + dx] * xp[iy * 64 + ix];
        }
    }
    acc += bias[c];
    float sc = gamma[c] * rsqrtf(var[c] + EPS_BN);
    float v  = (acc - mean[c]) * sc + beta[c];
    out[idx] = fmaxf(v, 0.f);
}

// ---------------------------------------------------------------------------
// conv1: [256,16,32,32] -> [256,32,16,16]. LDS-staged per (image, 8-ch group).
__global__ void conv1_kernel(const float* __restrict__ in,
                             const float* __restrict__ w, const float* __restrict__ bias,
                             const float* __restrict__ gamma, const float* __restrict__ beta,
                             const float* __restrict__ mean, const float* __restrict__ var,
                             float* __restrict__ out) {
    __shared__ float in_s[16384];
    __shared__ float w_s[1152];
    __shared__ float sc_s[8], sh_s[8];
    int b = blockIdx.x >> 2, cg = blockIdx.x & 3;
    int t = threadIdx.x;
    const float4* ip4 = (const float4*)(in + (size_t)b * 16384);
    float4* is4 = (float4*)in_s;
    for (int i = t; i < 4096; i += 256) is4[i] = ip4[i];
    for (int i = t; i < 1152; i += 256) w_s[i] = w[cg * 1152 + i];
    if (t < 8) {
        int c = cg * 8 + t;
        float sc = gamma[c] * rsqrtf(var[c] + EPS_BN);
        sc_s[t] = sc;
        sh_s[t] = (bias[c] - mean[c]) * sc + beta[c];
    }
    __syncthreads();
    int xo = t & 15, yo = t >> 4;
    float acc[8];
#pragma unroll
    for (int c = 0; c < 8; ++c) acc[c] = 0.f;
    int iy0 = 2 * yo - 1, ix0 = 2 * xo - 1;
    for (int ci = 0; ci < 16; ++ci) {
        const float* base = in_s + ci * 1024;
        float r[9];
#pragma unroll
        for (int dy = 0; dy < 3; ++dy) {
            int iy = iy0 + dy;
            int iyc = iy < 0 ? 0 : iy;
#pragma unroll
            for (int dx = 0; dx < 3; ++dx) {
                int ix = ix0 + dx;
                int ixc = ix < 0 ? 0 : ix;
                float v = base[iyc * 32 + ixc];
                r[dy * 3 + dx] = (iy >= 0 && ix >= 0) ? v : 0.f;
            }
        }
#pragma unroll
        for (int c = 0; c < 8; ++c) {
            const float* wp = w_s + (c * 16 + ci) * 9;
#pragma unroll
            for (int k = 0; k < 9; ++k) acc[c] = fmaf(wp[k], r[k], acc[c]);
        }
    }
#pragma unroll
    for (int c = 0; c < 8; ++c) {
        float v = fmaf(acc[c], sc_s[c], sh_s[c]);
        out[((size_t)(b * 32 + cg * 8 + c) * 16 + yo) * 16 + xo] = fmaxf(v, 0.f);
    }
}

// ---------------------------------------------------------------------------
// conv2: [256,32,16,16] -> [256,64,8,8]. LDS-staged per (image, 16-ch group).
__global__ void conv2_kernel(const float* __restrict__ in,
                             const float* __restrict__ w, const float* __restrict__ bias,
                             const float* __restrict__ gamma, const float* __restrict__ beta,
                             const float* __restrict__ mean, const float* __restrict__ var,
                             float* __restrict__ out) {
    __shared__ float in_s[8192];
    __shared__ float w_s[4608];
    __shared__ float sc_s[16], sh_s[16];
    int b = blockIdx.x >> 2, cg = blockIdx.x & 3;
    int t = threadIdx.x;
    const float4* ip4 = (const float4*)(in + (size_t)b * 8192);
    float4* is4 = (float4*)in_s;
    for (int i = t; i < 2048; i += 256) is4[i] = ip4[i];
    for (int i = t; i < 4608; i += 256) w_s[i] = w[cg * 4608 + i];
    if (t < 16) {
        int c = cg * 16 + t;
        float sc = gamma[c] * rsqrtf(var[c] + EPS_BN);
        sc_s[t] = sc;
        sh_s[t] = (bias[c] - mean[c]) * sc + beta[c];
    }
    __syncthreads();
    int xo = t & 7, yo = (t >> 3) & 7, cs = t >> 6;
    float acc[4];
#pragma unroll
    for (int l = 0; l < 4; ++l) acc[l] = 0.f;
    int iy0 = 2 * yo - 1, ix0 = 2 * xo - 1;
    for (int ci = 0; ci < 32; ++ci) {
        const float* base = in_s + ci * 256;
        float r[9];
#pragma unroll
        for (int dy = 0; dy < 3; ++dy) {
            int iy = iy0 + dy;
            int iyc = iy < 0 ? 0 : iy;
#pragma unroll
            for (int dx = 0; dx < 3; ++dx) {
                int ix = ix0 + dx;
                int ixc = ix < 0 ? 0 : ix;
                float v = base[iyc * 16 + ixc];
                r[dy * 3 + dx] = (iy >= 0 && ix >= 0) ? v : 0.f;
            }
        }
#pragma unroll
        for (int l = 0; l < 4; ++l) {
            const float* wp = w_s + ((cs * 4 + l) * 32 + ci) * 9;
#pragma unroll
            for (int k = 0; k < 9; ++k) acc[l] = fmaf(wp[k], r[k], acc[l]);
        }
    }
#pragma unroll
    for (int l = 0; l < 4; ++l) {
        int c = cg * 16 + cs * 4 + l;
        float v = fmaf(acc[l], sc_s[cs * 4 + l], sh_s[cs * 4 + l]);
        out[((size_t)(b * 64 + c) * 8 + yo) * 8 + xo] = fmaxf(v, 0.f);
    }
}

// ---------------------------------------------------------------------------
// qnorm: y2 [256,64,8,8] -> transpose -> L2 normalize -> bf16; qsq from the
// bf16-rounded values. Also initializes mind2 (+inf) for the dist kernel.
__global__ void qnorm_kernel(const float* __restrict__ y2,
                             __bf16* __restrict__ q, float* __restrict__ qsq,
                             unsigned int* __restrict__ mind2) {
    __shared__ float  L1s[4096];
    __shared__ __bf16 L2s[4096];
    int b = blockIdx.x, t = threadIdx.x;          // 64 threads
    mind2[b * 64 + t] = 0x7f800000u;              // +inf init
    const float* src = y2 + (size_t)b * 4096;
    for (int i = t; i < 4096; i += 64) L1s[i] = src[i];
    __syncthreads();
    int p = t;
    float ss = 0.f;
    for (int d = 0; d < 64; ++d) { float v = L1s[d * 64 + p]; ss += v * v; }
    float inv = 1.f / fmaxf(sqrtf(ss), 1e-12f);
    float q2 = 0.f;
    for (int d = 0; d < 64; ++d) {
        float v = L1s[d * 64 + p] * inv;
        __bf16 bv = (__bf16)v;
        L2s[p * 64 + d] = bv;
        float fb = (float)bv;
        q2 += fb * fb;
    }
    qsq[b * 64 + p] = q2;
    __syncthreads();
    for (int p2 = 0; p2 < 64; ++p2)
        q[((size_t)(b * 64 + p2)) * 64 + t] = L2s[p2 * 64 + t];
}

// ---------------------------------------------------------------------------
// mbnorm v2: 16 threads/row, float4 per thread, 4-step 16-lane reduction,
// vectorized 8B bf16 store. msq := 1 in dist (unit rows).
__global__ void mbnorm_kernel(const float* __restrict__ mb,
                              __bf16* __restrict__ mbbf) {
    int tid = blockIdx.x * 256 + threadIdx.x;
    int row = tid >> 4, sub = tid & 15;
    const float4 v = *(const float4*)(mb + (size_t)row * 64 + sub * 4);
    float ss = v.x * v.x + v.y * v.y + v.z * v.z + v.w * v.w;
#pragma unroll
    for (int o = 1; o < 16; o <<= 1) ss += __shfl_xor(ss, o, 64);
    float inv = 1.f / fmaxf(sqrtf(ss), 1e-12f);
    v4bf o;
    o[0] = (__bf16)(v.x * inv);
    o[1] = (__bf16)(v.y * inv);
    o[2] = (__bf16)(v.z * inv);
    o[3] = (__bf16)(v.w * inv);
    *(v4bf*)(mbbf + (size_t)row * 64 + sub * 4) = o;
}

// ---------------------------------------------------------------------------
// dist v17 = v16 (operand swap, bound 4) + #pragma unroll 1 on the mt loop.
// R7 diagnosis: v16 spilled NOT because of the swap (it passed, layout proven)
// but because its mt loop was FULLY unrolled — all 8 tilecomp bodies exposed
// to the scheduler -> overlapped transients blew past 128 regs (v14's proven
// loop used unroll 1 + rolling regs; v16 dropped that discipline). With
// unroll 1: live = b 32 + pair accs 32 + aA/aB 16 + tmax 4 + Z 4 + addr ~10
// ~= 98 regs. launch_bounds' 2nd arg only guides the ALLOCATOR; HW residency
// follows actual allocation: if alloc <= 102 -> 5 blocks/CU under bounds(,4)
// (20 waves x 102 = 2040 <= 2048 regs/SIMD-pool, LDS 5x32KB = 160KB exact)
// -> MfmaUtil ~85-92, ~290us. If alloc in (102,128] -> 4 blocks, v14-parity
// ~334us floor. Kill-check: GB-scale FETCH/WRITE = spill = diagnosis wrong,
// revert to v14 permanently.
__global__ __launch_bounds__(256, 4)
void dist_kernel(const __bf16* __restrict__ q, const float* __restrict__ qsq,
                 const __bf16* __restrict__ mb,
                 unsigned int* __restrict__ mind2) {
    __shared__ __align__(16) __bf16 Bs[2][CHUNK * 64];   // 2 x 16 KB
    const int t = threadIdx.x;
    const int wave = t >> 6, lane = t & 63;
    const int c16 = lane & 15;        // q-col within tile / m-row selector
    const int kblk = lane >> 4;       // 0..3: k-granule / C-row group
    const int qbase = blockIdx.x * 256 + wave * 64;
    const int slice = blockIdx.y;

    // B operand: q fragments, 4 q-tiles x 2 ksteps (32 VGPR, persistent).
    v8bf b[4][2];
#pragma unroll
    for (int qt = 0; qt < 4; ++qt)
#pragma unroll
        for (int ks = 0; ks < 2; ++ks)
            b[qt][ks] = *(const v8bf*)(q + (size_t)(qbase + qt * 16 + c16) * 64
                                         + ks * 32 + kblk * 8);

    // per-(lane, q-tile) running max over this lane's m-rows (kblk*4..+3)
    float tmax[4];
#pragma unroll
    for (int qt = 0; qt < 4; ++qt) tmax[qt] = -3.0e38f;

    v4f Z;                            // hoisted zero C-operand (4 regs)
#pragma unroll
    for (int r = 0; r < 4; ++r) Z[r] = 0.f;

    // staging: granule g=j*256+t -> row g>>3, slot (g&7)^(row&7); granule j
    // at LDS offset j*4096 (j*32 ≡ 0 mod 8 -> swizzle j-invariant).
    const int r0 = t >> 3, c0 = (t & 7) ^ (r0 & 7);
    const __bf16* gp = mb + (size_t)slice * SLICE_LEN * 64 + r0 * 64 + c0 * 8;
    const int wbase = wave * 1024;

    // prologue: chunk 0 -> buf 0 (4 granules of 4KB)
#pragma unroll
    for (int j = 0; j < 4; ++j) {
        gload_lds16(gp, (char*)Bs[0] + j * 4096 + wbase);
        gp += 2048;
    }

    // ds_read offsets: data k-granule κ = kblk + 4*ks at physical slot
    // κ ^ (row&7); row = c16 -> byte = c16*128 + ((κ ^ (lane&7))<<4).
    const int rowb = c16 * 128;
    int offk[2];
#pragma unroll
    for (int ks = 0; ks < 2; ++ks) offk[ks] = (((kblk + 4 * ks) ^ (lane & 7)) << 4);

#define MF16(A, B, C) __builtin_amdgcn_mfma_f32_16x16x32_bf16((A), (B), (C), 0, 0, 0)

    // one m-tile: 4 indep chains (one per q-tile) of length 2, then in-lane
    // fold of each chain's 4 m-rows into the running tmax.
    auto tilecomp = [&](v8bf a0, v8bf a1) {
        v4f c0 = MF16(a0, b[0][0], Z);
        v4f c1 = MF16(a0, b[1][0], Z);
        v4f c2 = MF16(a0, b[2][0], Z);
        v4f c3 = MF16(a0, b[3][0], Z);
        c0 = MF16(a1, b[0][1], c0);
        c1 = MF16(a1, b[1][1], c1);
        c2 = MF16(a1, b[2][1], c2);
        c3 = MF16(a1, b[3][1], c3);
        tmax[0] = fmaxf(tmax[0], fmaxf(fmaxf(c0[0], c0[1]), fmaxf(c0[2], c0[3])));
        tmax[1] = fmaxf(tmax[1], fmaxf(fmaxf(c1[0], c1[1]), fmaxf(c1[2], c1[3])));
        tmax[2] = fmaxf(tmax[2], fmaxf(fmaxf(c2[0], c2[1]), fmaxf(c2[2], c2[3])));
        tmax[3] = fmaxf(tmax[3], fmaxf(fmaxf(c3[0], c3[1]), fmaxf(c3[2], c3[3])));
    };

    auto step = [&](const char* bp, char* pdst, bool more) {
        __syncthreads();              // drains staging (vmcnt0) + sync
        if (more) {
#pragma unroll
            for (int j = 0; j < 4; ++j) {
                gload_lds16(gp, pdst + j * 4096 + wbase);
                gp += 2048;
            }
        }
        const char* tp = bp + rowb;
        // 8 m-tiles of 16 rows; rolling prefetch with named regs. unroll 1
        // (v14's proven discipline) bounds scheduler overlap to one pair:
        // transient pressure stays ~98 regs instead of 8 bodies in flight.
        v8bf aA0 = *(const v8bf*)(tp + offk[0]);
        v8bf aA1 = *(const v8bf*)(tp + offk[1]);
#pragma unroll 1
        for (int mt = 0; mt < 8; mt += 2) {
            v8bf aB0 = *(const v8bf*)(tp + (mt + 1) * 2048 + offk[0]);
            v8bf aB1 = *(const v8bf*)(tp + (mt + 1) * 2048 + offk[1]);
            tilecomp(aA0, aA1);
            if (mt + 2 < 8) {
                aA0 = *(const v8bf*)(tp + (mt + 2) * 2048 + offk[0]);
                aA1 = *(const v8bf*)(tp + (mt + 2) * 2048 + offk[1]);
            }
            tilecomp(aB0, aB1);
        }
    };

    for (int ch = 0; ch < NCHUNKS; ch += 2) {
        step((const char*)Bs[0], (char*)Bs[1], ch + 1 < NCHUNKS);
        step((const char*)Bs[1], (char*)Bs[0], ch + 2 < NCHUNKS);
    }
#undef MF16

    // combine the 4 kblk groups (disjoint m-row subsets) per q-col
#pragma unroll
    for (int qt = 0; qt < 4; ++qt) {
        float v = tmax[qt];
        v = fmaxf(v, __shfl_xor(v, 16, 64));
        v = fmaxf(v, __shfl_xor(v, 32, 64));
        tmax[qt] = v;
    }
    if (kblk == 0) {
#pragma unroll
        for (int qt = 0; qt < 4; ++qt) {
            int qi = qbase + qt * 16 + c16;
            // d^2 = qsq + |m|^2 - 2 dot, |m|^2 := 1 (unit rows)
            float dd = fmaxf(qsq[qi] + 1.0f - 2.0f * tmax[qt], 0.f);
            atomicMin(mind2 + qi, __float_as_uint(dd));
        }
    }
}

// finalize: out[b] = max_p sqrt(mind2[b*64+p])
__global__ void finalize_kernel(const unsigned int* __restrict__ mind2,
                                float* __restrict__ out) {
    int b = blockIdx.x, l = threadIdx.x;
    float v = __uint_as_float(mind2[b * 64 + l]);
    float d = sqrtf(fmaxf(v, 0.f));
#pragma unroll
    for (int o = 1; o < 64; o <<= 1) d = fmaxf(d, __shfl_xor(d, o, 64));
    if (l == 0) out[b] = d;
}

// ---------------------------------------------------------------------------
extern "C" void kernel_launch(void* const* d_in, const int* in_sizes, int n_in,
                              void* d_out, int out_size, void* d_ws, size_t ws_size,
                              hipStream_t stream) {
    (void)in_sizes; (void)n_in; (void)out_size; (void)ws_size;
    const float* x     = (const float*)d_in[0];
    const float* mbank = (const float*)d_in[1];
    const float* w0 = (const float*)d_in[2],  *b0 = (const float*)d_in[3];
    const float* g0 = (const float*)d_in[4],  *be0 = (const float*)d_in[5];
    const float* mn0 = (const float*)d_in[6], *vr0 = (const float*)d_in[7];
    const float* w1 = (const float*)d_in[8],  *b1 = (const float*)d_in[9];
    const float* g1 = (const float*)d_in[10], *be1 = (const float*)d_in[11];
    const float* mn1 = (const float*)d_in[12], *vr1 = (const float*)d_in[13];
    const float* w2 = (const float*)d_in[14], *b2 = (const float*)d_in[15];
    const float* g2 = (const float*)d_in[16], *be2 = (const float*)d_in[17];
    const float* mn2 = (const float*)d_in[18], *vr2 = (const float*)d_in[19];

    char* ws = (char*)d_ws;
    float*        y0    = (float*)(ws + 0);              // 16.78 MB
    float*        y1    = (float*)(ws + 16777216);       // 8.39 MB
    float*        y2    = (float*)(ws + 25165824);       // 4.19 MB
    __bf16*       qbf   = (__bf16*)(ws + 29360128);      // 2.10 MB
    float*        qsq   = (float*)(ws + 31457280);       // 64 KB
    __bf16*       mbbf  = (__bf16*)(ws + 31522816);      // 33.55 MB
    unsigned int* mind2 = (unsigned int*)(ws + 66125824);// 64 KB

    conv0_kernel<<<16384, 256, 0, stream>>>(x, w0, b0, g0, be0, mn0, vr0, y0);
    conv1_kernel<<<1024, 256, 0, stream>>>(y0, w1, b1, g1, be1, mn1, vr1, y1);
    conv2_kernel<<<1024, 256, 0, stream>>>(y1, w2, b2, g2, be2, mn2, vr2, y2);
    qnorm_kernel<<<256, 64, 0, stream>>>(y2, qbf, qsq, mind2);
    mbnorm_kernel<<<16384, 256, 0, stream>>>(mbank, mbbf);
    dist_kernel<<<dim3(64, SLICES), 256, 0, stream>>>(qbf, qsq, mbbf, mind2);
    finalize_kernel<<<256, 64, 0, stream>>>(mind2, (float*)d_out);
}

// Round 9
// 554.259 us; speedup vs baseline: 6.3964x; 1.1116x over previous
//
#include <hip/hip_runtime.h>
#include <math.h>

typedef __bf16 v8bf __attribute__((ext_vector_type(8)));
typedef __bf16 v4bf __attribute__((ext_vector_type(4)));
typedef float  v16f __attribute__((ext_vector_type(16)));
typedef float  v4f  __attribute__((ext_vector_type(4)));

#define EPS_BN 1e-5f
#define Q_TOTAL 16384
#define N_MEM   262144
#define SLICES  64
#define SLICE_LEN (N_MEM / SLICES)   /* 4096 */
#define CHUNK   128
#define NCHUNKS (SLICE_LEN / CHUNK)  /* 32 */

// async global->LDS, 16B/lane. LDS dest is wave-uniform base + lane*16, so
// the bank swizzle must be folded into the GLOBAL source addresses.
__device__ __forceinline__ void gload_lds16(const void* g, void* l) {
    __builtin_amdgcn_global_load_lds(
        (const __attribute__((address_space(1))) void*)g,
        (__attribute__((address_space(3))) void*)l, 16, 0, 0);
}

// ---------------------------------------------------------------------------
// conv0: [256,1,64,64] -> [256,16,32,32], 3x3 s2 p1 + BN + ReLU
__global__ void conv0_kernel(const float* __restrict__ x,
                             const float* __restrict__ w, const float* __restrict__ bias,
                             const float* __restrict__ gamma, const float* __restrict__ beta,
                             const float* __restrict__ mean, const float* __restrict__ var,
                             float* __restrict__ out) {
    int idx = blockIdx.x * 256 + threadIdx.x;
    int xo = idx & 31, yo = (idx >> 5) & 31, c = (idx >> 10) & 15, b = idx >> 14;
    const float* xp = x + (size_t)b * 4096;
    const float* wc = w + c * 9;
    float acc = 0.f;
#pragma unroll
    for (int dy = 0; dy < 3; ++dy) {
        int iy = 2 * yo + dy - 1;
        if (iy < 0) continue;
#pragma unroll
        for (int dx = 0; dx < 3; ++dx) {
            int ix = 2 * xo + dx - 1;
            if (ix < 0) continue;
            acc += wc[dy * 3 + dx] * xp[iy * 64 + ix];
        }
    }
    acc += bias[c];
    float sc = gamma[c] * rsqrtf(var[c] + EPS_BN);
    float v  = (acc - mean[c]) * sc + beta[c];
    out[idx] = fmaxf(v, 0.f);
}

// ---------------------------------------------------------------------------
// conv1: [256,16,32,32] -> [256,32,16,16]. LDS-staged per (image, 8-ch group).
__global__ void conv1_kernel(const float* __restrict__ in,
                             const float* __restrict__ w, const float* __restrict__ bias,
                             const float* __restrict__ gamma, const float* __restrict__ beta,
                             const float* __restrict__ mean, const float* __restrict__ var,
                             float* __restrict__ out) {
    __shared__ float in_s[16384];
    __shared__ float w_s[1152];
    __shared__ float sc_s[8], sh_s[8];
    int b = blockIdx.x >> 2, cg = blockIdx.x & 3;
    int t = threadIdx.x;
    const float4* ip4 = (const float4*)(in + (size_t)b * 16384);
    float4* is4 = (float4*)in_s;
    for (int i = t; i < 4096; i += 256) is4[i] = ip4[i];
    for (int i = t; i < 1152; i += 256) w_s[i] = w[cg * 1152 + i];
    if (t < 8) {
        int c = cg * 8 + t;
        float sc = gamma[c] * rsqrtf(var[c] + EPS_BN);
        sc_s[t] = sc;
        sh_s[t] = (bias[c] - mean[c]) * sc + beta[c];
    }
    __syncthreads();
    int xo = t & 15, yo = t >> 4;
    float acc[8];
#pragma unroll
    for (int c = 0; c < 8; ++c) acc[c] = 0.f;
    int iy0 = 2 * yo - 1, ix0 = 2 * xo - 1;
    for (int ci = 0; ci < 16; ++ci) {
        const float* base = in_s + ci * 1024;
        float r[9];
#pragma unroll
        for (int dy = 0; dy < 3; ++dy) {
            int iy = iy0 + dy;
            int iyc = iy < 0 ? 0 : iy;
#pragma unroll
            for (int dx = 0; dx < 3; ++dx) {
                int ix = ix0 + dx;
                int ixc = ix < 0 ? 0 : ix;
                float v = base[iyc * 32 + ixc];
                r[dy * 3 + dx] = (iy >= 0 && ix >= 0) ? v : 0.f;
            }
        }
#pragma unroll
        for (int c = 0; c < 8; ++c) {
            const float* wp = w_s + (c * 16 + ci) * 9;
#pragma unroll
            for (int k = 0; k < 9; ++k) acc[c] = fmaf(wp[k], r[k], acc[c]);
        }
    }
#pragma unroll
    for (int c = 0; c < 8; ++c) {
        float v = fmaf(acc[c], sc_s[c], sh_s[c]);
        out[((size_t)(b * 32 + cg * 8 + c) * 16 + yo) * 16 + xo] = fmaxf(v, 0.f);
    }
}

// ---------------------------------------------------------------------------
// conv2: [256,32,16,16] -> [256,64,8,8]. LDS-staged per (image, 16-ch group).
__global__ void conv2_kernel(const float* __restrict__ in,
                             const float* __restrict__ w, const float* __restrict__ bias,
                             const float* __restrict__ gamma, const float* __restrict__ beta,
                             const float* __restrict__ mean, const float* __restrict__ var,
                             float* __restrict__ out) {
    __shared__ float in_s[8192];
    __shared__ float w_s[4608];
    __shared__ float sc_s[16], sh_s[16];
    int b = blockIdx.x >> 2, cg = blockIdx.x & 3;
    int t = threadIdx.x;
    const float4* ip4 = (const float4*)(in + (size_t)b * 8192);
    float4* is4 = (float4*)in_s;
    for (int i = t; i < 2048; i += 256) is4[i] = ip4[i];
    for (int i = t; i < 4608; i += 256) w_s[i] = w[cg * 4608 + i];
    if (t < 16) {
        int c = cg * 16 + t;
        float sc = gamma[c] * rsqrtf(var[c] + EPS_BN);
        sc_s[t] = sc;
        sh_s[t] = (bias[c] - mean[c]) * sc + beta[c];
    }
    __syncthreads();
    int xo = t & 7, yo = (t >> 3) & 7, cs = t >> 6;
    float acc[4];
#pragma unroll
    for (int l = 0; l < 4; ++l) acc[l] = 0.f;
    int iy0 = 2 * yo - 1, ix0 = 2 * xo - 1;
    for (int ci = 0; ci < 32; ++ci) {
        const float* base = in_s + ci * 256;
        float r[9];
#pragma unroll
        for (int dy = 0; dy < 3; ++dy) {
            int iy = iy0 + dy;
            int iyc = iy < 0 ? 0 : iy;
#pragma unroll
            for (int dx = 0; dx < 3; ++dx) {
                int ix = ix0 + dx;
                int ixc = ix < 0 ? 0 : ix;
                float v = base[iyc * 16 + ixc];
                r[dy * 3 + dx] = (iy >= 0 && ix >= 0) ? v : 0.f;
            }
        }
#pragma unroll
        for (int l = 0; l < 4; ++l) {
            const float* wp = w_s + ((cs * 4 + l) * 32 + ci) * 9;
#pragma unroll
            for (int k = 0; k < 9; ++k) acc[l] = fmaf(wp[k], r[k], acc[l]);
        }
    }
#pragma unroll
    for (int l = 0; l < 4; ++l) {
        int c = cg * 16 + cs * 4 + l;
        float v = fmaf(acc[l], sc_s[cs * 4 + l], sh_s[cs * 4 + l]);
        out[((size_t)(b * 64 + c) * 8 + yo) * 8 + xo] = fmaxf(v, 0.f);
    }
}

// ---------------------------------------------------------------------------
// qnorm v2: was 64 threads/block (16K threads on a 524K-lane machine, 192
// serial iterations/thread). Now 256 threads: a 4-lane quad per pixel, 16
// dims/lane, shfl_xor(1,2) quad-reduce for the norm, vectorized 2x16B bf16
// stores (quad writes one contiguous 128B row). No LDS.
__global__ void qnorm_kernel(const float* __restrict__ y2,
                             __bf16* __restrict__ q, float* __restrict__ qsq,
                             unsigned int* __restrict__ mind2) {
    int b = blockIdx.x, t = threadIdx.x;          // 256 threads
    if (t < 64) mind2[b * 64 + t] = 0x7f800000u;  // +inf init
    int p = t >> 2, dg = t & 3;                   // pixel, 16-dim group
    const float* src = y2 + (size_t)b * 4096 + p; // [64 ch][64 px], stride 64
    float v[16];
    float ss = 0.f;
#pragma unroll
    for (int i = 0; i < 16; ++i) {
        v[i] = src[(dg * 16 + i) * 64];
        ss += v[i] * v[i];
    }
    ss += __shfl_xor(ss, 1, 64);                  // quad lanes share pixel p
    ss += __shfl_xor(ss, 2, 64);
    float inv = 1.f / fmaxf(sqrtf(ss), 1e-12f);
    v8bf o0, o1;
    float q2 = 0.f;
#pragma unroll
    for (int i = 0; i < 16; ++i) {
        __bf16 bv = (__bf16)(v[i] * inv);
        if (i < 8) o0[i] = bv; else o1[i - 8] = bv;
        float fb = (float)bv;
        q2 += fb * fb;                            // qsq from bf16-rounded
    }
    q2 += __shfl_xor(q2, 1, 64);
    q2 += __shfl_xor(q2, 2, 64);
    if (dg == 0) qsq[b * 64 + p] = q2;
    __bf16* dst = q + ((size_t)(b * 64 + p)) * 64 + dg * 16;
    *(v8bf*)dst = o0;
    *(v8bf*)(dst + 8) = o1;
}

// ---------------------------------------------------------------------------
// mbnorm v2: 16 threads/row, float4 per thread, 4-step 16-lane reduction,
// vectorized 8B bf16 store. msq := 1 in dist (unit rows).
__global__ void mbnorm_kernel(const float* __restrict__ mb,
                              __bf16* __restrict__ mbbf) {
    int tid = blockIdx.x * 256 + threadIdx.x;
    int row = tid >> 4, sub = tid & 15;
    const float4 v = *(const float4*)(mb + (size_t)row * 64 + sub * 4);
    float ss = v.x * v.x + v.y * v.y + v.z * v.z + v.w * v.w;
#pragma unroll
    for (int o = 1; o < 16; o <<= 1) ss += __shfl_xor(ss, o, 64);
    float inv = 1.f / fmaxf(sqrtf(ss), 1e-12f);
    v4bf o;
    o[0] = (__bf16)(v.x * inv);
    o[1] = (__bf16)(v.y * inv);
    o[2] = (__bf16)(v.z * inv);
    o[3] = (__bf16)(v.w * inv);
    *(v4bf*)(mbbf + (size_t)row * 64 + sub * 4) = o;
}

// ---------------------------------------------------------------------------
// dist v18 = v14 VERBATIM (measured 333.6us, MfmaUtil 79.4% of the 264.9us
// 16x16-pipe floor — best structure found). Closing the operand-swap arc
// (R5-R8): the swap was layout-correct but (a) occupancy averaged ~3.3
// blocks/CU regardless of register headroom (ramp/tail-dominated at grid
// 4096), and (b) its in-lane fold serialized 16 fmax behind every 8-MFMA
// group -> issue efficiency 70.7% < v14's 79.4% (8 indep chains, fold per
// 16 MFMAs). v14's remaining 21%: barrier drain + dep stalls at ~3.3 avg
// resident blocks — structural for this 2-barrier K-loop shape.
__global__ __launch_bounds__(256, 4)
void dist_kernel(const __bf16* __restrict__ q, const float* __restrict__ qsq,
                 const __bf16* __restrict__ mb,
                 unsigned int* __restrict__ mind2) {
    __shared__ __align__(16) __bf16 Bs[2][CHUNK * 64];   // 2 x 16 KB
    const int t = threadIdx.x;
    const int wave = t >> 6, lane = t & 63;
    const int c16 = lane & 15;        // m-col within tile / q-row for A
    const int kblk = lane >> 4;       // 0..3: k-subblock
    const int mbase = blockIdx.x * 256 + wave * 64;
    const int slice = blockIdx.y;

    // A fragments: 4 strips x 2 ksteps (32 VGPR).
    v8bf a[4][2];
#pragma unroll
    for (int s = 0; s < 4; ++s)
#pragma unroll
        for (int ks = 0; ks < 2; ++ks)
            a[s][ks] = *(const v8bf*)(q + (size_t)(mbase + s * 16 + c16) * 64
                                        + ks * 32 + kblk * 8);

    float tmax[4][4];
#pragma unroll
    for (int s = 0; s < 4; ++s)
#pragma unroll
        for (int r = 0; r < 4; ++r) tmax[s][r] = -3.0e38f;

    v4f Z;                            // hoisted zero C-operand (4 regs)
#pragma unroll
    for (int r = 0; r < 4; ++r) Z[r] = 0.f;

    // staging: granule g=j*256+t -> row g>>3, slot (g&7)^(row&7); granule j
    // at LDS offset j*4096 (j*32 ≡ 0 mod 8 -> swizzle j-invariant).
    const int r0 = t >> 3, c0 = (t & 7) ^ (r0 & 7);
    const __bf16* gp = mb + (size_t)slice * SLICE_LEN * 64 + r0 * 64 + c0 * 8;
    const int wbase = wave * 1024;

    // prologue: chunk 0 -> buf 0 (4 granules of 4KB)
#pragma unroll
    for (int j = 0; j < 4; ++j) {
        gload_lds16(gp, (char*)Bs[0] + j * 4096 + wbase);
        gp += 2048;
    }

    // ds_read offsets: data k-slot κ = kblk + 4*ks lives at physical slot
    // κ ^ (row&7); row = c16 -> byte = c16*128 + ((κ ^ (lane&7))<<4).
    const int rowb = c16 * 128;
    int offk[2];
#pragma unroll
    for (int ks = 0; ks < 2; ++ks) offk[ks] = (((kblk + 4 * ks) ^ (lane & 7)) << 4);

    auto step = [&](const char* bp, char* pdst, bool more) {
        __syncthreads();              // drains staging (vmcnt0) + sync
        if (more) {
#pragma unroll
            for (int j = 0; j < 4; ++j) {
                gload_lds16(gp, pdst + j * 4096 + wbase);
                gp += 2048;
            }
        }
        const char* tp = bp + rowb;
        v8bf be[2], bo[2];
#pragma unroll
        for (int ks = 0; ks < 2; ++ks) {
            be[ks] = *(const v8bf*)(tp + offk[ks]);           // m-tile 0
            bo[ks] = *(const v8bf*)(tp + 2048 + offk[ks]);    // m-tile 1
        }
#pragma unroll 1
        for (int p = 0; p < 4; ++p) {
            v4f Ae[4], Ao[4];
            // ks0: 8 independent chain heads
#pragma unroll
            for (int s = 0; s < 4; ++s)
                Ae[s] = __builtin_amdgcn_mfma_f32_16x16x32_bf16(a[s][0], be[0], Z, 0, 0, 0);
#pragma unroll
            for (int s = 0; s < 4; ++s)
                Ao[s] = __builtin_amdgcn_mfma_f32_16x16x32_bf16(a[s][0], bo[0], Z, 0, 0, 0);
            // ks1: finish the chains (dep gap = 8 issues)
#pragma unroll
            for (int s = 0; s < 4; ++s)
                Ae[s] = __builtin_amdgcn_mfma_f32_16x16x32_bf16(a[s][1], be[1], Ae[s], 0, 0, 0);
#pragma unroll
            for (int s = 0; s < 4; ++s)
                Ao[s] = __builtin_amdgcn_mfma_f32_16x16x32_bf16(a[s][1], bo[1], Ao[s], 0, 0, 0);
            // reload be/bo in place for the next pair (WAR safe: in-order issue)
            if (p < 3) {
                const char* tn = tp + (p + 1) * 4096;
#pragma unroll
                for (int ks = 0; ks < 2; ++ks) {
                    be[ks] = *(const v8bf*)(tn + offk[ks]);
                    bo[ks] = *(const v8bf*)(tn + 2048 + offk[ks]);
                }
            }
            // fold both m-tiles: fmax(fmax(.,.),.) -> v_max3_f32
#pragma unroll
            for (int s = 0; s < 4; ++s)
#pragma unroll
                for (int r = 0; r < 4; ++r)
                    tmax[s][r] = fmaxf(fmaxf(Ae[s][r], Ao[s][r]), tmax[s][r]);
        }
    };

    for (int ch = 0; ch < NCHUNKS; ch += 2) {
        step((const char*)Bs[0], (char*)Bs[1], ch + 1 < NCHUNKS);
        step((const char*)Bs[1], (char*)Bs[0], ch + 2 < NCHUNKS);
    }

    // cross-lane max over the 16 m-cols (lanes sharing lane>>4)
#pragma unroll
    for (int s = 0; s < 4; ++s)
#pragma unroll
        for (int r = 0; r < 4; ++r) {
            float v = tmax[s][r];
            v = fmaxf(v, __shfl_xor(v, 1, 64));
            v = fmaxf(v, __shfl_xor(v, 2, 64));
            v = fmaxf(v, __shfl_xor(v, 4, 64));
            v = fmaxf(v, __shfl_xor(v, 8, 64));
            tmax[s][r] = v;
        }
    if (c16 == 0) {
#pragma unroll
        for (int s = 0; s < 4; ++s)
#pragma unroll
            for (int r = 0; r < 4; ++r) {
                int m = mbase + s * 16 + kblk * 4 + r;  // C/D row map
                // d^2 = qsq + |m|^2 - 2 dot, |m|^2 := 1 (unit rows)
                float dd = fmaxf(qsq[m] + 1.0f - 2.0f * tmax[s][r], 0.f);
                atomicMin(mind2 + m, __float_as_uint(dd));
            }
    }
}

// finalize: out[b] = max_p sqrt(mind2[b*64+p])
__global__ void finalize_kernel(const unsigned int* __restrict__ mind2,
                                float* __restrict__ out) {
    int b = blockIdx.x, l = threadIdx.x;
    float v = __uint_as_float(mind2[b * 64 + l]);
    float d = sqrtf(fmaxf(v, 0.f));
#pragma unroll
    for (int o = 1; o < 64; o <<= 1) d = fmaxf(d, __shfl_xor(d, o, 64));
    if (l == 0) out[b] = d;
}

// ---------------------------------------------------------------------------
extern "C" void kernel_launch(void* const* d_in, const int* in_sizes, int n_in,
                              void* d_out, int out_size, void* d_ws, size_t ws_size,
                              hipStream_t stream) {
    (void)in_sizes; (void)n_in; (void)out_size; (void)ws_size;
    const float* x     = (const float*)d_in[0];
    const float* mbank = (const float*)d_in[1];
    const float* w0 = (const float*)d_in[2],  *b0 = (const float*)d_in[3];
    const float* g0 = (const float*)d_in[4],  *be0 = (const float*)d_in[5];
    const float* mn0 = (const float*)d_in[6], *vr0 = (const float*)d_in[7];
    const float* w1 = (const float*)d_in[8],  *b1 = (const float*)d_in[9];
    const float* g1 = (const float*)d_in[10], *be1 = (const float*)d_in[11];
    const float* mn1 = (const float*)d_in[12], *vr1 = (const float*)d_in[13];
    const float* w2 = (const float*)d_in[14], *b2 = (const float*)d_in[15];
    const float* g2 = (const float*)d_in[16], *be2 = (const float*)d_in[17];
    const float* mn2 = (const float*)d_in[18], *vr2 = (const float*)d_in[19];

    char* ws = (char*)d_ws;
    float*        y0    = (float*)(ws + 0);              // 16.78 MB
    float*        y1    = (float*)(ws + 16777216);       // 8.39 MB
    float*        y2    = (float*)(ws + 25165824);       // 4.19 MB
    __bf16*       qbf   = (__bf16*)(ws + 29360128);      // 2.10 MB
    float*        qsq   = (float*)(ws + 31457280);       // 64 KB
    __bf16*       mbbf  = (__bf16*)(ws + 31522816);      // 33.55 MB
    unsigned int* mind2 = (unsigned int*)(ws + 66125824);// 64 KB

    conv0_kernel<<<16384, 256, 0, stream>>>(x, w0, b0, g0, be0, mn0, vr0, y0);
    conv1_kernel<<<1024, 256, 0, stream>>>(y0, w1, b1, g1, be1, mn1, vr1, y1);
    conv2_kernel<<<1024, 256, 0, stream>>>(y1, w2, b2, g2, be2, mn2, vr2, y2);
    qnorm_kernel<<<256, 256, 0, stream>>>(y2, qbf, qsq, mind2);
    mbnorm_kernel<<<16384, 256, 0, stream>>>(mbank, mbbf);
    dist_kernel<<<dim3(64, SLICES), 256, 0, stream>>>(qbf, qsq, mbbf, mind2);
    finalize_kernel<<<256, 64, 0, stream>>>(mind2, (float*)d_out);
}

// Round 10
// 551.910 us; speedup vs baseline: 6.4236x; 1.0043x over previous
//
#include <hip/hip_runtime.h>
#include <math.h>

typedef __bf16 v8bf __attribute__((ext_vector_type(8)));
typedef __bf16 v4bf __attribute__((ext_vector_type(4)));
typedef float  v16f __attribute__((ext_vector_type(16)));
typedef float  v4f  __attribute__((ext_vector_type(4)));

#define EPS_BN 1e-5f
#define Q_TOTAL 16384
#define N_MEM   262144
#define SLICES  64
#define SLICE_LEN (N_MEM / SLICES)   /* 4096 */
#define CHUNK   128
#define NCHUNKS (SLICE_LEN / CHUNK)  /* 32 */

// async global->LDS, 16B/lane. LDS dest is wave-uniform base + lane*16, so
// the bank swizzle must be folded into the GLOBAL source addresses.
__device__ __forceinline__ void gload_lds16(const void* g, void* l) {
    __builtin_amdgcn_global_load_lds(
        (const __attribute__((address_space(1))) void*)g,
        (__attribute__((address_space(3))) void*)l, 16, 0, 0);
}

// ---------------------------------------------------------------------------
// conv0: [256,1,64,64] -> [256,16,32,32], 3x3 s2 p1 + BN + ReLU
__global__ void conv0_kernel(const float* __restrict__ x,
                             const float* __restrict__ w, const float* __restrict__ bias,
                             const float* __restrict__ gamma, const float* __restrict__ beta,
                             const float* __restrict__ mean, const float* __restrict__ var,
                             float* __restrict__ out) {
    int idx = blockIdx.x * 256 + threadIdx.x;
    int xo = idx & 31, yo = (idx >> 5) & 31, c = (idx >> 10) & 15, b = idx >> 14;
    const float* xp = x + (size_t)b * 4096;
    const float* wc = w + c * 9;
    float acc = 0.f;
#pragma unroll
    for (int dy = 0; dy < 3; ++dy) {
        int iy = 2 * yo + dy - 1;
        if (iy < 0) continue;
#pragma unroll
        for (int dx = 0; dx < 3; ++dx) {
            int ix = 2 * xo + dx - 1;
            if (ix < 0) continue;
            acc += wc[dy * 3 + dx] * xp[iy * 64 + ix];
        }
    }
    acc += bias[c];
    float sc = gamma[c] * rsqrtf(var[c] + EPS_BN);
    float v  = (acc - mean[c]) * sc + beta[c];
    out[idx] = fmaxf(v, 0.f);
}

// ---------------------------------------------------------------------------
// conv1 v2: [256,16,32,32] -> [256,32,16,16]. Input staged in LDS (per-lane
// varying), but WEIGHTS now read directly from GLOBAL with wave-uniform
// addresses -> compiler emits s_load via the scalar cache. v1 read weights
// from LDS: 1152 wave-uniform ds_read_b32/thread (~5.8 cyc each) dominated
// the kernel (~5x the FMA cost) — classic LDS-issue-pipe bind on broadcast
// data. SMEM runs parallel to VALU; LDS insts drop 1296 -> 144 per thread.
__global__ void conv1_kernel(const float* __restrict__ in,
                             const float* __restrict__ w, const float* __restrict__ bias,
                             const float* __restrict__ gamma, const float* __restrict__ beta,
                             const float* __restrict__ mean, const float* __restrict__ var,
                             float* __restrict__ out) {
    __shared__ float in_s[16384];
    __shared__ float sc_s[8], sh_s[8];
    int b = blockIdx.x >> 2, cg = blockIdx.x & 3;
    int t = threadIdx.x;
    const float4* ip4 = (const float4*)(in + (size_t)b * 16384);
    float4* is4 = (float4*)in_s;
    for (int i = t; i < 4096; i += 256) is4[i] = ip4[i];
    if (t < 8) {
        int c = cg * 8 + t;
        float sc = gamma[c] * rsqrtf(var[c] + EPS_BN);
        sc_s[t] = sc;
        sh_s[t] = (bias[c] - mean[c]) * sc + beta[c];
    }
    __syncthreads();
    const float* wg = w + cg * 1152;          // uniform base -> s_load path
    int xo = t & 15, yo = t >> 4;
    float acc[8];
#pragma unroll
    for (int c = 0; c < 8; ++c) acc[c] = 0.f;
    int iy0 = 2 * yo - 1, ix0 = 2 * xo - 1;
    for (int ci = 0; ci < 16; ++ci) {
        const float* base = in_s + ci * 1024;
        float r[9];
#pragma unroll
        for (int dy = 0; dy < 3; ++dy) {
            int iy = iy0 + dy;
            int iyc = iy < 0 ? 0 : iy;
#pragma unroll
            for (int dx = 0; dx < 3; ++dx) {
                int ix = ix0 + dx;
                int ixc = ix < 0 ? 0 : ix;
                float v = base[iyc * 32 + ixc];
                r[dy * 3 + dx] = (iy >= 0 && ix >= 0) ? v : 0.f;
            }
        }
#pragma unroll
        for (int c = 0; c < 8; ++c) {
            const float* wp = wg + (c * 16 + ci) * 9;   // uniform address
#pragma unroll
            for (int k = 0; k < 9; ++k) acc[c] = fmaf(wp[k], r[k], acc[c]);
        }
    }
#pragma unroll
    for (int c = 0; c < 8; ++c) {
        float v = fmaf(acc[c], sc_s[c], sh_s[c]);
        out[((size_t)(b * 32 + cg * 8 + c) * 16 + yo) * 16 + xo] = fmaxf(v, 0.f);
    }
}

// ---------------------------------------------------------------------------
// conv2 v2: [256,32,16,16] -> [256,64,8,8]. Same weight de-LDS-ification as
// conv1 (cs = t>>6 is wave-uniform, so the weight address is uniform within
// each wave -> s_load). LDS drops 26 KB -> 8 KB (occupancy headroom).
__global__ void conv2_kernel(const float* __restrict__ in,
                             const float* __restrict__ w, const float* __restrict__ bias,
                             const float* __restrict__ gamma, const float* __restrict__ beta,
                             const float* __restrict__ mean, const float* __restrict__ var,
                             float* __restrict__ out) {
    __shared__ float in_s[8192];
    __shared__ float sc_s[16], sh_s[16];
    int b = blockIdx.x >> 2, cg = blockIdx.x & 3;
    int t = threadIdx.x;
    const float4* ip4 = (const float4*)(in + (size_t)b * 8192);
    float4* is4 = (float4*)in_s;
    for (int i = t; i < 2048; i += 256) is4[i] = ip4[i];
    if (t < 16) {
        int c = cg * 16 + t;
        float sc = gamma[c] * rsqrtf(var[c] + EPS_BN);
        sc_s[t] = sc;
        sh_s[t] = (bias[c] - mean[c]) * sc + beta[c];
    }
    __syncthreads();
    const float* wg = w + cg * 4608;          // uniform base -> s_load path
    int xo = t & 7, yo = (t >> 3) & 7, cs = t >> 6;
    float acc[4];
#pragma unroll
    for (int l = 0; l < 4; ++l) acc[l] = 0.f;
    int iy0 = 2 * yo - 1, ix0 = 2 * xo - 1;
    for (int ci = 0; ci < 32; ++ci) {
        const float* base = in_s + ci * 256;
        float r[9];
#pragma unroll
        for (int dy = 0; dy < 3; ++dy) {
            int iy = iy0 + dy;
            int iyc = iy < 0 ? 0 : iy;
#pragma unroll
            for (int dx = 0; dx < 3; ++dx) {
                int ix = ix0 + dx;
                int ixc = ix < 0 ? 0 : ix;
                float v = base[iyc * 16 + ixc];
                r[dy * 3 + dx] = (iy >= 0 && ix >= 0) ? v : 0.f;
            }
        }
#pragma unroll
        for (int l = 0; l < 4; ++l) {
            const float* wp = wg + ((cs * 4 + l) * 32 + ci) * 9;  // wave-uniform
#pragma unroll
            for (int k = 0; k < 9; ++k) acc[l] = fmaf(wp[k], r[k], acc[l]);
        }
    }
#pragma unroll
    for (int l = 0; l < 4; ++l) {
        int c = cg * 16 + cs * 4 + l;
        float v = fmaf(acc[l], sc_s[cs * 4 + l], sh_s[cs * 4 + l]);
        out[((size_t)(b * 64 + c) * 8 + yo) * 8 + xo] = fmaxf(v, 0.f);
    }
}

// ---------------------------------------------------------------------------
// qnorm v2 (R9, kept: non-dist bucket -9us): 256 threads, 4-lane quad per
// pixel, shfl_xor(1,2) quad-reduce, vectorized 2x16B bf16 stores. No LDS.
__global__ void qnorm_kernel(const float* __restrict__ y2,
                             __bf16* __restrict__ q, float* __restrict__ qsq,
                             unsigned int* __restrict__ mind2) {
    int b = blockIdx.x, t = threadIdx.x;          // 256 threads
    if (t < 64) mind2[b * 64 + t] = 0x7f800000u;  // +inf init
    int p = t >> 2, dg = t & 3;                   // pixel, 16-dim group
    const float* src = y2 + (size_t)b * 4096 + p; // [64 ch][64 px], stride 64
    float v[16];
    float ss = 0.f;
#pragma unroll
    for (int i = 0; i < 16; ++i) {
        v[i] = src[(dg * 16 + i) * 64];
        ss += v[i] * v[i];
    }
    ss += __shfl_xor(ss, 1, 64);                  // quad lanes share pixel p
    ss += __shfl_xor(ss, 2, 64);
    float inv = 1.f / fmaxf(sqrtf(ss), 1e-12f);
    v8bf o0, o1;
    float q2 = 0.f;
#pragma unroll
    for (int i = 0; i < 16; ++i) {
        __bf16 bv = (__bf16)(v[i] * inv);
        if (i < 8) o0[i] = bv; else o1[i - 8] = bv;
        float fb = (float)bv;
        q2 += fb * fb;                            // qsq from bf16-rounded
    }
    q2 += __shfl_xor(q2, 1, 64);
    q2 += __shfl_xor(q2, 2, 64);
    if (dg == 0) qsq[b * 64 + p] = q2;
    __bf16* dst = q + ((size_t)(b * 64 + p)) * 64 + dg * 16;
    *(v8bf*)dst = o0;
    *(v8bf*)(dst + 8) = o1;
}

// ---------------------------------------------------------------------------
// mbnorm v2: 16 threads/row, float4 per thread, 4-step 16-lane reduction,
// vectorized 8B bf16 store. msq := 1 in dist (unit rows).
__global__ void mbnorm_kernel(const float* __restrict__ mb,
                              __bf16* __restrict__ mbbf) {
    int tid = blockIdx.x * 256 + threadIdx.x;
    int row = tid >> 4, sub = tid & 15;
    const float4 v = *(const float4*)(mb + (size_t)row * 64 + sub * 4);
    float ss = v.x * v.x + v.y * v.y + v.z * v.z + v.w * v.w;
#pragma unroll
    for (int o = 1; o < 16; o <<= 1) ss += __shfl_xor(ss, o, 64);
    float inv = 1.f / fmaxf(sqrtf(ss), 1e-12f);
    v4bf o;
    o[0] = (__bf16)(v.x * inv);
    o[1] = (__bf16)(v.y * inv);
    o[2] = (__bf16)(v.z * inv);
    o[3] = (__bf16)(v.w * inv);
    *(v4bf*)(mbbf + (size_t)row * 64 + sub * 4) = o;
}

// ---------------------------------------------------------------------------
// dist v18 = v14 VERBATIM (R9 re-measured: 331.7us, MfmaUtil 79.9% of the
// 264.9us 16x16-pipe floor — banked best. The remaining ~20% is the 2-barrier
// K-loop's drain+skew at ~3.3 avg resident blocks; R3/R6/R7 proved more
// residency spills and R8 proved the in-lane-fold alternative issues worse).
__global__ __launch_bounds__(256, 4)
void dist_kernel(const __bf16* __restrict__ q, const float* __restrict__ qsq,
                 const __bf16* __restrict__ mb,
                 unsigned int* __restrict__ mind2) {
    __shared__ __align__(16) __bf16 Bs[2][CHUNK * 64];   // 2 x 16 KB
    const int t = threadIdx.x;
    const int wave = t >> 6, lane = t & 63;
    const int c16 = lane & 15;        // m-col within tile / q-row for A
    const int kblk = lane >> 4;       // 0..3: k-subblock
    const int mbase = blockIdx.x * 256 + wave * 64;
    const int slice = blockIdx.y;

    // A fragments: 4 strips x 2 ksteps (32 VGPR).
    v8bf a[4][2];
#pragma unroll
    for (int s = 0; s < 4; ++s)
#pragma unroll
        for (int ks = 0; ks < 2; ++ks)
            a[s][ks] = *(const v8bf*)(q + (size_t)(mbase + s * 16 + c16) * 64
                                        + ks * 32 + kblk * 8);

    float tmax[4][4];
#pragma unroll
    for (int s = 0; s < 4; ++s)
#pragma unroll
        for (int r = 0; r < 4; ++r) tmax[s][r] = -3.0e38f;

    v4f Z;                            // hoisted zero C-operand (4 regs)
#pragma unroll
    for (int r = 0; r < 4; ++r) Z[r] = 0.f;

    // staging: granule g=j*256+t -> row g>>3, slot (g&7)^(row&7); granule j
    // at LDS offset j*4096 (j*32 ≡ 0 mod 8 -> swizzle j-invariant).
    const int r0 = t >> 3, c0 = (t & 7) ^ (r0 & 7);
    const __bf16* gp = mb + (size_t)slice * SLICE_LEN * 64 + r0 * 64 + c0 * 8;
    const int wbase = wave * 1024;

    // prologue: chunk 0 -> buf 0 (4 granules of 4KB)
#pragma unroll
    for (int j = 0; j < 4; ++j) {
        gload_lds16(gp, (char*)Bs[0] + j * 4096 + wbase);
        gp += 2048;
    }

    // ds_read offsets: data k-slot κ = kblk + 4*ks lives at physical slot
    // κ ^ (row&7); row = c16 -> byte = c16*128 + ((κ ^ (lane&7))<<4).
    const int rowb = c16 * 128;
    int offk[2];
#pragma unroll
    for (int ks = 0; ks < 2; ++ks) offk[ks] = (((kblk + 4 * ks) ^ (lane & 7)) << 4);

    auto step = [&](const char* bp, char* pdst, bool more) {
        __syncthreads();              // drains staging (vmcnt0) + sync
        if (more) {
#pragma unroll
            for (int j = 0; j < 4; ++j) {
                gload_lds16(gp, pdst + j * 4096 + wbase);
                gp += 2048;
            }
        }
        const char* tp = bp + rowb;
        v8bf be[2], bo[2];
#pragma unroll
        for (int ks = 0; ks < 2; ++ks) {
            be[ks] = *(const v8bf*)(tp + offk[ks]);           // m-tile 0
            bo[ks] = *(const v8bf*)(tp + 2048 + offk[ks]);    // m-tile 1
        }
#pragma unroll 1
        for (int p = 0; p < 4; ++p) {
            v4f Ae[4], Ao[4];
            // ks0: 8 independent chain heads
#pragma unroll
            for (int s = 0; s < 4; ++s)
                Ae[s] = __builtin_amdgcn_mfma_f32_16x16x32_bf16(a[s][0], be[0], Z, 0, 0, 0);
#pragma unroll
            for (int s = 0; s < 4; ++s)
                Ao[s] = __builtin_amdgcn_mfma_f32_16x16x32_bf16(a[s][0], bo[0], Z, 0, 0, 0);
            // ks1: finish the chains (dep gap = 8 issues)
#pragma unroll
            for (int s = 0; s < 4; ++s)
                Ae[s] = __builtin_amdgcn_mfma_f32_16x16x32_bf16(a[s][1], be[1], Ae[s], 0, 0, 0);
#pragma unroll
            for (int s = 0; s < 4; ++s)
                Ao[s] = __builtin_amdgcn_mfma_f32_16x16x32_bf16(a[s][1], bo[1], Ao[s], 0, 0, 0);
            // reload be/bo in place for the next pair (WAR safe: in-order issue)
            if (p < 3) {
                const char* tn = tp + (p + 1) * 4096;
#pragma unroll
                for (int ks = 0; ks < 2; ++ks) {
                    be[ks] = *(const v8bf*)(tn + offk[ks]);
                    bo[ks] = *(const v8bf*)(tn + 2048 + offk[ks]);
                }
            }
            // fold both m-tiles: fmax(fmax(.,.),.) -> v_max3_f32
#pragma unroll
            for (int s = 0; s < 4; ++s)
#pragma unroll
                for (int r = 0; r < 4; ++r)
                    tmax[s][r] = fmaxf(fmaxf(Ae[s][r], Ao[s][r]), tmax[s][r]);
        }
    };

    for (int ch = 0; ch < NCHUNKS; ch += 2) {
        step((const char*)Bs[0], (char*)Bs[1], ch + 1 < NCHUNKS);
        step((const char*)Bs[1], (char*)Bs[0], ch + 2 < NCHUNKS);
    }

    // cross-lane max over the 16 m-cols (lanes sharing lane>>4)
#pragma unroll
    for (int s = 0; s < 4; ++s)
#pragma unroll
        for (int r = 0; r < 4; ++r) {
            float v = tmax[s][r];
            v = fmaxf(v, __shfl_xor(v, 1, 64));
            v = fmaxf(v, __shfl_xor(v, 2, 64));
            v = fmaxf(v, __shfl_xor(v, 4, 64));
            v = fmaxf(v, __shfl_xor(v, 8, 64));
            tmax[s][r] = v;
        }
    if (c16 == 0) {
#pragma unroll
        for (int s = 0; s < 4; ++s)
#pragma unroll
            for (int r = 0; r < 4; ++r) {
                int m = mbase + s * 16 + kblk * 4 + r;  // C/D row map
                // d^2 = qsq + |m|^2 - 2 dot, |m|^2 := 1 (unit rows)
                float dd = fmaxf(qsq[m] + 1.0f - 2.0f * tmax[s][r], 0.f);
                atomicMin(mind2 + m, __float_as_uint(dd));
            }
    }
}

// finalize: out[b] = max_p sqrt(mind2[b*64+p])
__global__ void finalize_kernel(const unsigned int* __restrict__ mind2,
                                float* __restrict__ out) {
    int b = blockIdx.x, l = threadIdx.x;
    float v = __uint_as_float(mind2[b * 64 + l]);
    float d = sqrtf(fmaxf(v, 0.f));
#pragma unroll
    for (int o = 1; o < 64; o <<= 1) d = fmaxf(d, __shfl_xor(d, o, 64));
    if (l == 0) out[b] = d;
}

// ---------------------------------------------------------------------------
extern "C" void kernel_launch(void* const* d_in, const int* in_sizes, int n_in,
                              void* d_out, int out_size, void* d_ws, size_t ws_size,
                              hipStream_t stream) {
    (void)in_sizes; (void)n_in; (void)out_size; (void)ws_size;
    const float* x     = (const float*)d_in[0];
    const float* mbank = (const float*)d_in[1];
    const float* w0 = (const float*)d_in[2],  *b0 = (const float*)d_in[3];
    const float* g0 = (const float*)d_in[4],  *be0 = (const float*)d_in[5];
    const float* mn0 = (const float*)d_in[6], *vr0 = (const float*)d_in[7];
    const float* w1 = (const float*)d_in[8],  *b1 = (const float*)d_in[9];
    const float* g1 = (const float*)d_in[10], *be1 = (const float*)d_in[11];
    const float* mn1 = (const float*)d_in[12], *vr1 = (const float*)d_in[13];
    const float* w2 = (const float*)d_in[14], *b2 = (const float*)d_in[15];
    const float* g2 = (const float*)d_in[16], *be2 = (const float*)d_in[17];
    const float* mn2 = (const float*)d_in[18], *vr2 = (const float*)d_in[19];

    char* ws = (char*)d_ws;
    float*        y0    = (float*)(ws + 0);              // 16.78 MB
    float*        y1    = (float*)(ws + 16777216);       // 8.39 MB
    float*        y2    = (float*)(ws + 25165824);       // 4.19 MB
    __bf16*       qbf   = (__bf16*)(ws + 29360128);      // 2.10 MB
    float*        qsq   = (float*)(ws + 31457280);       // 64 KB
    __bf16*       mbbf  = (__bf16*)(ws + 31522816);      // 33.55 MB
    unsigned int* mind2 = (unsigned int*)(ws + 66125824);// 64 KB

    conv0_kernel<<<16384, 256, 0, stream>>>(x, w0, b0, g0, be0, mn0, vr0, y0);
    conv1_kernel<<<1024, 256, 0, stream>>>(y0, w1, b1, g1, be1, mn1, vr1, y1);
    conv2_kernel<<<1024, 256, 0, stream>>>(y1, w2, b2, g2, be2, mn2, vr2, y2);
    qnorm_kernel<<<256, 256, 0, stream>>>(y2, qbf, qsq, mind2);
    mbnorm_kernel<<<16384, 256, 0, stream>>>(mbank, mbbf);
    dist_kernel<<<dim3(64, SLICES), 256, 0, stream>>>(qbf, qsq, mbbf, mind2);
    finalize_kernel<<<256, 64, 0, stream>>>(mind2, (float*)d_out);
}